// Round 13
// baseline (513.257 us; speedup 1.0000x reference)
//
#include <hip/hip_runtime.h>
#include <hip/hip_fp16.h>

#define H 128
#define NEG 0.2f
#define EPSBN 1e-5f
#define BM 32

__device__ __forceinline__ float lrelu(float v){ return v >= 0.f ? v : NEG*v; }

union HU { __half2 h; unsigned int u; };

typedef __attribute__((ext_vector_type(8))) short bf16x8;
typedef __attribute__((ext_vector_type(4))) float f32x4;
#define MFMA16(a,b,c) __builtin_amdgcn_mfma_f32_16x16x32_bf16(a,b,c,0,0,0)

__device__ __forceinline__ unsigned short bf16_rn(float x){
  unsigned int u = __float_as_uint(x);
  u += 0x7fffu + ((u >> 16) & 1u);
  return (unsigned short)(u >> 16);
}
__device__ __forceinline__ float bf16f(unsigned short h){
  return __uint_as_float(((unsigned int)h) << 16);
}

__device__ __forceinline__ void asplit(const float* As, int aofs, bf16x8& ah, bf16x8& al){
  float av[8];
  *reinterpret_cast<float4*>(&av[0]) = *reinterpret_cast<const float4*>(&As[aofs]);
  *reinterpret_cast<float4*>(&av[4]) = *reinterpret_cast<const float4*>(&As[aofs+4]);
  #pragma unroll
  for (int j=0;j<8;j++){
    unsigned short h = bf16_rn(av[j]);
    ah[j] = (short)h;
    al[j] = (short)bf16_rn(av[j] - bf16f(h));
  }
}

// ---------- prep: N1|N2 = [We_top; We_bot] @ Wl  (per layer) ----------
__global__ void prep1_kernel(const float* __restrict__ We, const float* __restrict__ Wl,
                             float* __restrict__ Ntmp){
  int l = blockIdx.x >> 7;
  int k = blockIdx.x & 127;
  int j = threadIdx.x;          // 0..255
  __shared__ float WeS[2*H];
  if (j < H) WeS[j] = We[(size_t)(l*2*H + k)*H + j];
  else       WeS[j] = We[(size_t)(l*2*H + 128 + k)*H + (j-128)];
  __syncthreads();
  const float* wl = Wl + (size_t)l*H*H;
  int sel = (j >> 7) << 7;      // 0 or 128
  int jj = j & 127;
  float acc = 0.f;
  #pragma unroll 8
  for (int m=0;m<H;m++) acc += WeS[sel + m] * wl[m*H + jj];
  Ntmp[(size_t)(l*H + k)*256 + j] = acc;
}

// ---------- prep: Mcomb = Wg @ [N1|N2] ----------
__global__ void prep2_kernel(const float* __restrict__ Wg, const float* __restrict__ Ntmp,
                             float* __restrict__ Mcomb){
  int l = blockIdx.x >> 7;
  int k = blockIdx.x & 127;
  int j = threadIdx.x;          // 0..255
  __shared__ float WgS[H];
  if (j < H) WgS[j] = Wg[(size_t)(l*H + k)*H + j];
  __syncthreads();
  const float* nt = Ntmp + (size_t)l*H*256;
  float acc = 0.f;
  #pragma unroll 8
  for (int m=0;m<H;m++) acc += WgS[m] * nt[m*256 + j];
  Mcomb[(size_t)(l*H + k)*256 + j] = acc;
}

// ---------- prep: split Mcomb -> bf16 hi/lo in MFMA fragment order ----------
// layout: [l][ks][ct][lane][j]  (ks: K/32, ct: col-tile/16, lane 0..63, j 0..7)
__global__ void prep3_kernel(const float* __restrict__ Mcomb,
                             unsigned short* __restrict__ Mfh, unsigned short* __restrict__ Mfl){
  int bid = blockIdx.x;             // l*64 + ks*16 + ct
  int l  = bid >> 6;
  int ks = (bid >> 4) & 3;
  int ct = bid & 15;
  int lane = threadIdx.x;           // 0..63
  const float* M = Mcomb + (size_t)l*H*256;
  size_t base = ((((size_t)l*4 + ks)*16 + ct)*64 + lane)*8;
  int col = ct*16 + (lane & 15);
  int g = lane >> 4;
  #pragma unroll
  for (int j=0;j<8;j++){
    int k = ks*32 + 8*g + j;
    float v = M[(size_t)k*256 + col];
    unsigned short hi = bf16_rn(v);
    unsigned short lo = bf16_rn(v - bf16f(hi));
    Mfh[base + j] = hi;
    Mfl[base + j] = lo;
  }
}

// ---------- prep: c1 = be@Wl ; c2 = bg@Wl + bl ----------
__global__ void prepc_kernel(const float* __restrict__ be, const float* __restrict__ bg,
                             const float* __restrict__ bl, const float* __restrict__ Wl,
                             float* __restrict__ c1c2){
  int l = blockIdx.x;
  int j = threadIdx.x;          // 0..127
  const float* wl = Wl + (size_t)l*H*H;
  float a1=0.f, a2=0.f;
  for (int m=0;m<H;m++){ float w = wl[m*H + j]; a1 += be[l*H+m]*w; a2 += bg[l*H+m]*w; }
  c1c2[l*2*H + j]     = a1;
  c1c2[l*2*H + H + j] = a2 + bl[l*H + j];
}

// ---------- in-degree count + per-edge rank (rank = order within destination) ----------
__global__ void deg_kernel(const int* __restrict__ ei, int E, int* __restrict__ degI,
                           unsigned short* __restrict__ rankA){
  int e = blockIdx.x*blockDim.x + threadIdx.x;
  if (e < E){
    int r = atomicAdd(&degI[ei[E + e]], 1);
    rankA[e] = (unsigned short)r;
  }
}

// ---------- CSR build: block-wise inclusive scan of degrees ----------
__global__ void scan1_kernel(const int* __restrict__ degI, int n,
                             int* __restrict__ incl, int* __restrict__ bsum){
  int i = blockIdx.x*256 + threadIdx.x;
  __shared__ int sh[256];
  int v = (i < n) ? degI[i] : 0;
  sh[threadIdx.x] = v;
  __syncthreads();
  for (int ofs=1; ofs<256; ofs<<=1){
    int t = (threadIdx.x >= ofs) ? sh[threadIdx.x - ofs] : 0;
    __syncthreads();
    sh[threadIdx.x] += t;
    __syncthreads();
  }
  if (i < n) incl[i] = sh[threadIdx.x];
  if (threadIdx.x == 255) bsum[blockIdx.x] = sh[255];
}

__global__ void scan2_kernel(int* __restrict__ bsum, int nb){
  __shared__ int sh[256];
  int v = (threadIdx.x < nb) ? bsum[threadIdx.x] : 0;
  sh[threadIdx.x] = v;
  __syncthreads();
  for (int ofs=1; ofs<256; ofs<<=1){
    int t = (threadIdx.x >= ofs) ? sh[threadIdx.x - ofs] : 0;
    __syncthreads();
    sh[threadIdx.x] += t;
    __syncthreads();
  }
  if (threadIdx.x < nb) bsum[threadIdx.x] = sh[threadIdx.x] - v;  // exclusive
}

__global__ void scan3_kernel(const int* __restrict__ incl, const int* __restrict__ degI,
                             const int* __restrict__ bexcl, int n, int E,
                             int* __restrict__ rowptr){
  int i = blockIdx.x*256 + threadIdx.x;
  if (i < n){
    int start = incl[i] - degI[i] + bexcl[blockIdx.x];
    rowptr[i] = start;
    if (i == n-1) rowptr[n] = E;
  }
}

// ---------- atomic-free fill: pos = rowptr[dst] + rank ----------
__global__ void fill_kernel(const int* __restrict__ ei, int E,
                            const int* __restrict__ rowptr, const unsigned short* __restrict__ rankA,
                            unsigned short* __restrict__ csr_src){
  int e = blockIdx.x*256 + threadIdx.x;
  if (e < E){
    int c = ei[E + e];
    int pos = rowptr[c] + (int)rankA[e];
    csr_src[pos] = (unsigned short)ei[e];
  }
}

// ---------- graph boundary offsets from sorted batch ----------
__global__ void gofs_kernel(const int* __restrict__ batch, int n, int B, int* __restrict__ gofs){
  int i = blockIdx.x*256 + threadIdx.x;
  if (i >= n) return;
  if (i == 0){
    int b0 = batch[0];
    for (int g=0; g<=b0; g++) gofs[g] = 0;
  } else {
    int bp = batch[i-1], bc = batch[i];
    for (int g=bp+1; g<=bc; g++) gofs[g] = i;
  }
  if (i == n-1){
    int bl = batch[n-1];
    for (int g=bl+1; g<=B; g++) gofs[g] = n;
  }
}

// ---------- MFMA GEMM: [U|V] = A @ M (128x256), split-bf16: U 3-term, V 2-term ----------
// BM=32, 256 thr = 4 waves (rowtile = w&1, colgroup = w>>1).
// Ping-pong named-register prefetch of next-ks B fragments (c* / n* sets).
#define KSBODY(KS, C, N, PREF) \
  { bf16x8 ah, al; asplit(As, arow_*132 + (KS)*32 + agrp, ah, al); \
    if (PREF){ int nb = fb + ((KS)+1)*1024; \
      N##U0h = Bh[nb];     N##U1h = Bh[nb+64];  N##U2h = Bh[nb+128]; N##U3h = Bh[nb+192]; \
      N##U0l = Bl[nb];     N##U1l = Bl[nb+64];  N##U2l = Bl[nb+128]; N##U3l = Bl[nb+192]; \
      N##V0h = Bh[nb+512]; N##V1h = Bh[nb+576]; N##V2h = Bh[nb+640]; N##V3h = Bh[nb+704]; } \
    accU[0]=MFMA16(ah,C##U0h,accU[0]); accU[0]=MFMA16(al,C##U0h,accU[0]); accU[0]=MFMA16(ah,C##U0l,accU[0]); \
    accV[0]=MFMA16(ah,C##V0h,accV[0]); accV[0]=MFMA16(al,C##V0h,accV[0]); \
    accU[1]=MFMA16(ah,C##U1h,accU[1]); accU[1]=MFMA16(al,C##U1h,accU[1]); accU[1]=MFMA16(ah,C##U1l,accU[1]); \
    accV[1]=MFMA16(ah,C##V1h,accV[1]); accV[1]=MFMA16(al,C##V1h,accV[1]); \
    accU[2]=MFMA16(ah,C##U2h,accU[2]); accU[2]=MFMA16(al,C##U2h,accU[2]); accU[2]=MFMA16(ah,C##U2l,accU[2]); \
    accV[2]=MFMA16(ah,C##V2h,accV[2]); accV[2]=MFMA16(al,C##V2h,accV[2]); \
    accU[3]=MFMA16(ah,C##U3h,accU[3]); accU[3]=MFMA16(al,C##U3h,accU[3]); accU[3]=MFMA16(ah,C##U3l,accU[3]); \
    accV[3]=MFMA16(ah,C##V3h,accV[3]); accV[3]=MFMA16(al,C##V3h,accV[3]); }

template<int XF>
__global__ __launch_bounds__(256)
void gemm_kernel(const float* __restrict__ Zin, const float* __restrict__ bnp,
                 const unsigned short* __restrict__ Mfh, const unsigned short* __restrict__ Mfl,
                 const float* __restrict__ c1c2, const int* __restrict__ degI,
                 int n, float* __restrict__ pre, __half* __restrict__ Vh){
  __shared__ float As[32*132];      // [row][k] padded to 132
  int brow = blockIdx.x * BM;
  int t = threadIdx.x;

  int lane = t & 63;
  int w = t >> 6;
  int rowtile = w & 1, colgroup = w >> 1;
  const bf16x8* Bh = reinterpret_cast<const bf16x8*>(Mfh);
  const bf16x8* Bl = reinterpret_cast<const bf16x8*>(Mfl);
  int fb = colgroup*4*64 + lane;    // frag index (ks=0, ct=colgroup*4)

  // ---- issue ks0 B loads early (overlap with A staging) ----
  bf16x8 cU0h,cU1h,cU2h,cU3h, cU0l,cU1l,cU2l,cU3l, cV0h,cV1h,cV2h,cV3h;
  bf16x8 nU0h,nU1h,nU2h,nU3h, nU0l,nU1l,nU2l,nU3l, nV0h,nV1h,nV2h,nV3h;
  cU0h = Bh[fb];     cU1h = Bh[fb+64];  cU2h = Bh[fb+128]; cU3h = Bh[fb+192];
  cU0l = Bl[fb];     cU1l = Bl[fb+64];  cU2l = Bl[fb+128]; cU3l = Bl[fb+192];
  cV0h = Bh[fb+512]; cV1h = Bh[fb+576]; cV2h = Bh[fb+640]; cV3h = Bh[fb+704];

  // ---- stage A (all K) into LDS ----
  {
    int srow = t >> 3, sf = t & 7;
    int gr = brow + srow;
    bool act = (gr < n);
    const float* zrow = Zin + (size_t)gr*H;
    #pragma unroll
    for (int u=0; u<4; u++){
      int c4 = sf + 8*u;            // float4 index 0..31
      float4 g = make_float4(0.f,0.f,0.f,0.f);
      if (act) g = *reinterpret_cast<const float4*>(&zrow[c4*4]);
      if (XF){
        float4 sc4 = *reinterpret_cast<const float4*>(&bnp[c4*4]);
        float4 sh4 = *reinterpret_cast<const float4*>(&bnp[H + c4*4]);
        g.x = lrelu(g.x)*sc4.x + sh4.x;
        g.y = lrelu(g.y)*sc4.y + sh4.y;
        g.z = lrelu(g.z)*sc4.z + sh4.z;
        g.w = lrelu(g.w)*sc4.w + sh4.w;
      }
      *reinterpret_cast<float4*>(&As[srow*132 + c4*4]) = g;
    }
  }
  __syncthreads();

  f32x4 accU[4], accV[4];
  #pragma unroll
  for (int i=0;i<4;i++){
    accU[i] = (f32x4){0.f,0.f,0.f,0.f};
    accV[i] = (f32x4){0.f,0.f,0.f,0.f};
  }
  int arow_ = rowtile*16 + (lane & 15);
  int agrp  = (lane >> 4) << 3;     // 8*(lane>>4)

  KSBODY(0, c, n, 1)
  KSBODY(1, n, c, 1)
  KSBODY(2, c, n, 1)
  KSBODY(3, n, c, 0)

  // ---- epilogue: C/D layout col = lane&15, row = (lane>>4)*4 + reg ----
  int rowbase = brow + rowtile*16 + ((lane >> 4) << 2);
  float dg[4];
  #pragma unroll
  for (int r=0;r<4;r++){
    int gr = rowbase + r;
    dg[r] = (gr < n) ? (float)(degI[gr] + 1) : 0.f;
  }
  #pragma unroll
  for (int ctu=0; ctu<4; ctu++){
    int colU = colgroup*64 + ctu*16 + (lane & 15);
    float c1v = c1c2[colU], c2v = c1c2[H + colU];
    #pragma unroll
    for (int r=0;r<4;r++){
      int gr = rowbase + r;
      if (gr < n){
        float uu = accU[ctu][r], vv = accV[ctu][r];
        pre[(size_t)gr*H + colU] = dg[r]*(uu + c1v) + c2v + vv;
        Vh [(size_t)gr*H + colU] = __float2half(vv);
      }
    }
  }
}

// ---------- CSR aggregation + fused BN-stats partials (8-deep gather unroll) ----------
__global__ __launch_bounds__(256)
void agg_kernel(const int* __restrict__ rowptr, const unsigned short* __restrict__ csr_src,
                const __half* __restrict__ Vh, float* __restrict__ pre, int n,
                float* __restrict__ partial){
  int node = blockIdx.x*8 + (threadIdx.x >> 5);
  int lane = threadIdx.x & 31;
  float4 h4 = make_float4(0.f,0.f,0.f,0.f);
  float4 q4 = make_float4(0.f,0.f,0.f,0.f);
  if (node < n){
    int p  = rowptr[node];
    int pe = rowptr[node+1];
    const __half* Vb = Vh + lane*4;
    float4 a = make_float4(0.f,0.f,0.f,0.f);
    for (; p+8 <= pe; p+=8){
      int s0 = csr_src[p],   s1 = csr_src[p+1], s2 = csr_src[p+2], s3 = csr_src[p+3];
      int s4 = csr_src[p+4], s5 = csr_src[p+5], s6 = csr_src[p+6], s7 = csr_src[p+7];
      uint2 r0 = *reinterpret_cast<const uint2*>(&Vb[(size_t)s0*H]);
      uint2 r1 = *reinterpret_cast<const uint2*>(&Vb[(size_t)s1*H]);
      uint2 r2 = *reinterpret_cast<const uint2*>(&Vb[(size_t)s2*H]);
      uint2 r3 = *reinterpret_cast<const uint2*>(&Vb[(size_t)s3*H]);
      uint2 r4 = *reinterpret_cast<const uint2*>(&Vb[(size_t)s4*H]);
      uint2 r5 = *reinterpret_cast<const uint2*>(&Vb[(size_t)s5*H]);
      uint2 r6 = *reinterpret_cast<const uint2*>(&Vb[(size_t)s6*H]);
      uint2 r7 = *reinterpret_cast<const uint2*>(&Vb[(size_t)s7*H]);
      HU ua, ub;
      float2 fa, fb;
      ua.u=r0.x; ub.u=r0.y; fa=__half22float2(ua.h); fb=__half22float2(ub.h);
      a.x+=fa.x; a.y+=fa.y; a.z+=fb.x; a.w+=fb.y;
      ua.u=r1.x; ub.u=r1.y; fa=__half22float2(ua.h); fb=__half22float2(ub.h);
      a.x+=fa.x; a.y+=fa.y; a.z+=fb.x; a.w+=fb.y;
      ua.u=r2.x; ub.u=r2.y; fa=__half22float2(ua.h); fb=__half22float2(ub.h);
      a.x+=fa.x; a.y+=fa.y; a.z+=fb.x; a.w+=fb.y;
      ua.u=r3.x; ub.u=r3.y; fa=__half22float2(ua.h); fb=__half22float2(ub.h);
      a.x+=fa.x; a.y+=fa.y; a.z+=fb.x; a.w+=fb.y;
      ua.u=r4.x; ub.u=r4.y; fa=__half22float2(ua.h); fb=__half22float2(ub.h);
      a.x+=fa.x; a.y+=fa.y; a.z+=fb.x; a.w+=fb.y;
      ua.u=r5.x; ub.u=r5.y; fa=__half22float2(ua.h); fb=__half22float2(ub.h);
      a.x+=fa.x; a.y+=fa.y; a.z+=fb.x; a.w+=fb.y;
      ua.u=r6.x; ub.u=r6.y; fa=__half22float2(ua.h); fb=__half22float2(ub.h);
      a.x+=fa.x; a.y+=fa.y; a.z+=fb.x; a.w+=fb.y;
      ua.u=r7.x; ub.u=r7.y; fa=__half22float2(ua.h); fb=__half22float2(ub.h);
      a.x+=fa.x; a.y+=fa.y; a.z+=fb.x; a.w+=fb.y;
    }
    for (; p+2 <= pe; p+=2){
      int s0 = csr_src[p], s1 = csr_src[p+1];
      uint2 r0 = *reinterpret_cast<const uint2*>(&Vb[(size_t)s0*H]);
      uint2 r1 = *reinterpret_cast<const uint2*>(&Vb[(size_t)s1*H]);
      HU ua, ub;
      float2 fa, fb;
      ua.u=r0.x; ub.u=r0.y; fa=__half22float2(ua.h); fb=__half22float2(ub.h);
      a.x+=fa.x; a.y+=fa.y; a.z+=fb.x; a.w+=fb.y;
      ua.u=r1.x; ub.u=r1.y; fa=__half22float2(ua.h); fb=__half22float2(ub.h);
      a.x+=fa.x; a.y+=fa.y; a.z+=fb.x; a.w+=fb.y;
    }
    for (; p < pe; p++){
      int s = csr_src[p];
      uint2 r = *reinterpret_cast<const uint2*>(&Vb[(size_t)s*H]);
      HU ua, ub; ua.u = r.x; ub.u = r.y;
      float2 fa = __half22float2(ua.h), fb = __half22float2(ub.h);
      a.x += fa.x; a.y += fa.y; a.z += fb.x; a.w += fb.y;
    }
    float4* pp = reinterpret_cast<float4*>(&pre[(size_t)node*H + lane*4]);
    float4 pr = *pp;
    pr.x += a.x; pr.y += a.y; pr.z += a.z; pr.w += a.w;
    *pp = pr;
    h4.x = lrelu(pr.x); h4.y = lrelu(pr.y); h4.z = lrelu(pr.z); h4.w = lrelu(pr.w);
    q4.x = h4.x*h4.x;   q4.y = h4.y*h4.y;   q4.z = h4.z*h4.z;   q4.w = h4.w*h4.w;
  }
  __shared__ float4 red[8][32];
  int slot = threadIdx.x >> 5;
  red[slot][lane] = h4;
  __syncthreads();
  if (threadIdx.x < 32){
    float4 tt = red[0][threadIdx.x];
    #pragma unroll
    for (int r=1;r<8;r++){
      float4 v = red[r][threadIdx.x];
      tt.x += v.x; tt.y += v.y; tt.z += v.z; tt.w += v.w;
    }
    *reinterpret_cast<float4*>(&partial[(size_t)blockIdx.x*256 + threadIdx.x*4]) = tt;
  }
  __syncthreads();
  red[slot][lane] = q4;
  __syncthreads();
  if (threadIdx.x < 32){
    float4 tt = red[0][threadIdx.x];
    #pragma unroll
    for (int r=1;r<8;r++){
      float4 v = red[r][threadIdx.x];
      tt.x += v.x; tt.y += v.y; tt.z += v.z; tt.w += v.w;
    }
    *reinterpret_cast<float4*>(&partial[(size_t)blockIdx.x*256 + 128 + threadIdx.x*4]) = tt;
  }
}

// ---------- reduce partials -> bnsum[256]; last block finalizes scsh ----------
__global__ __launch_bounds__(256)
void redstats_kernel(const float* __restrict__ partial, int nb, float* __restrict__ bnsum,
                     const float* __restrict__ gamma, const float* __restrict__ beta,
                     float inv_n, float* __restrict__ scsh, int* __restrict__ cnt){
  int c = threadIdx.x;
  float acc = 0.f;
  for (int b = blockIdx.x; b < nb; b += 64)
    acc += partial[(size_t)b*256 + c];
  atomicAdd(&bnsum[c], acc);
  __threadfence();
  __shared__ int lastS;
  __syncthreads();
  if (threadIdx.x == 0){
    int prev = atomicAdd(cnt, 1);
    lastS = (prev == 63) ? 1 : 0;
  }
  __syncthreads();
  if (lastS && c < H){
    float s  = atomicAdd(&bnsum[c], 0.f);       // device-coherent read
    float ss = atomicAdd(&bnsum[H + c], 0.f);
    float mu  = s * inv_n;
    float var = ss * inv_n - mu*mu;
    float rs  = rsqrtf(fmaxf(var, 0.f) + EPSBN);
    float sc  = gamma[c] * rs;
    scsh[c]     = sc;
    scsh[H + c] = beta[c] - mu*sc;
  }
}

// ---------- fused pool + MLP head: one block per graph ----------
// pooled mean = (sc * sum(lrelu(pre)) + cnt*sh) / cnt  (pooling is linear in z2)
__global__ __launch_bounds__(256)
void head_kernel(const float* __restrict__ pre, const float* __restrict__ scsh,
                 const int* __restrict__ gofs,
                 const float* __restrict__ Wf1, const float* __restrict__ bf1,
                 const float* __restrict__ Wf2, const float* __restrict__ bf2,
                 const float* __restrict__ Wf3, const float* __restrict__ bf3,
                 float* __restrict__ out){
  int g = blockIdx.x;
  int t = threadIdx.x;
  int col = t & 127, half = t >> 7;
  int s = gofs[g], e = gofs[g+1];
  float acc = 0.f;
  for (int r = s + half; r < e; r += 2)
    acc += lrelu(pre[(size_t)r*H + col]);
  __shared__ float ps[2][128];
  __shared__ float pm[128], h1[128], h2[64];
  ps[half][col] = acc;
  __syncthreads();
  if (t < 128){
    float cntf = (float)(e - s);
    float cf = fmaxf(cntf, 1.f);
    float sum = ps[0][t] + ps[1][t];
    pm[t] = (scsh[t]*sum + scsh[H + t]*cntf) / cf;
  }
  __syncthreads();
  if (t < 128){
    float a = bf1[t];
    for (int k=0;k<H;k++) a += pm[k]*Wf1[k*H + t];
    h1[t] = lrelu(a);
  }
  __syncthreads();
  if (t < 64){
    float b = bf2[t];
    for (int k=0;k<H;k++) b += h1[k]*Wf2[k*64 + t];
    h2[t] = lrelu(b);
  }
  __syncthreads();
  if (t < 2){
    float o = bf3[t];
    for (int k=0;k<64;k++) o += h2[k]*Wf3[k*2 + t];
    out[g*2 + t] = o;
  }
}

extern "C" void kernel_launch(void* const* d_in, const int* in_sizes, int n_in,
                              void* d_out, int out_size, void* d_ws, size_t ws_size,
                              hipStream_t stream){
  const float* x     = (const float*)d_in[0];
  const int*   ei    = (const int*)d_in[1];
  const int*   batch = (const int*)d_in[3];
  const float* Wg    = (const float*)d_in[4];
  const float* bg    = (const float*)d_in[5];
  const float* We    = (const float*)d_in[6];
  const float* be    = (const float*)d_in[7];
  const float* Wl    = (const float*)d_in[8];
  const float* bl    = (const float*)d_in[9];
  const float* gamma = (const float*)d_in[10];
  const float* beta  = (const float*)d_in[11];
  const float* Wf1   = (const float*)d_in[12];
  const float* bf1   = (const float*)d_in[13];
  const float* Wf2   = (const float*)d_in[14];
  const float* bf2   = (const float*)d_in[15];
  const float* Wf3   = (const float*)d_in[16];
  const float* bf3   = (const float*)d_in[17];
  float* out = (float*)d_out;

  int n = in_sizes[0] / H;   // 50000
  int E = in_sizes[1] / 2;   // 800000
  int B = out_size / 2;      // 50

  int nagg = (n + 7)/8;      // agg/partial blocks

  char* ws = (char*)d_ws;
  size_t off = 0;
  auto alloc = [&](size_t bytes)->void*{ void* p = ws + off; off += (bytes + 255) & ~255ULL; return p; };
  float*  pre    = (float*)alloc((size_t)n*H*4);
  __half* Vh     = (__half*)alloc((size_t)n*H*2);
  float*  Mcomb  = (float*)alloc((size_t)3*H*256*4);
  float*  Ntmp   = (float*)alloc((size_t)3*H*256*4);
  unsigned short* Mfh = (unsigned short*)alloc((size_t)3*4*16*64*8*2);
  unsigned short* Mfl = (unsigned short*)alloc((size_t)3*4*16*64*8*2);
  float*  c1c2   = (float*)alloc(3*2*H*4);
  float*  scsh   = (float*)alloc(3*2*H*4);
  int*    incl   = (int*)alloc((size_t)n*4);
  int*    bsum   = (int*)alloc(256*4);
  int*    rowptr = (int*)alloc((size_t)(n+1)*4);
  unsigned short* rankA   = (unsigned short*)alloc((size_t)E*2);
  unsigned short* csr_src = (unsigned short*)alloc((size_t)E*2);
  int*    gofs   = (int*)alloc((size_t)(B+1)*4);
  float*  partial= (float*)alloc((size_t)nagg*256*4);
  char* zbase = ws + off;                 // ---- zeroed region starts ----
  float* bnsum  = (float*)alloc(3*2*H*4);
  int*   cnt    = (int*)alloc(3*4);
  int*   degI   = (int*)alloc((size_t)n*4);
  size_t zbytes = (size_t)((ws + off) - zbase);
  hipMemsetAsync(zbase, 0, zbytes, stream);

  prep1_kernel<<<3*H, 256, 0, stream>>>(We, Wl, Ntmp);
  prep2_kernel<<<3*H, 256, 0, stream>>>(Wg, Ntmp, Mcomb);
  prep3_kernel<<<3*64, 64, 0, stream>>>(Mcomb, Mfh, Mfl);
  prepc_kernel<<<3, 128, 0, stream>>>(be, bg, bl, Wl, c1c2);
  deg_kernel<<<(E+255)/256, 256, 0, stream>>>(ei, E, degI, rankA);

  int nb = (n + 255)/256;
  scan1_kernel<<<nb, 256, 0, stream>>>(degI, n, incl, bsum);
  scan2_kernel<<<1, 256, 0, stream>>>(bsum, nb);
  scan3_kernel<<<nb, 256, 0, stream>>>(incl, degI, bsum, n, E, rowptr);
  fill_kernel<<<(E+255)/256, 256, 0, stream>>>(ei, E, rowptr, rankA, csr_src);
  gofs_kernel<<<nb, 256, 0, stream>>>(batch, n, B, gofs);

  int gblocks = (n + BM - 1)/BM;
  size_t mstride = (size_t)4*16*64*8;   // shorts per layer
  for (int l=0; l<3; l++){
    if (l == 0)
      gemm_kernel<0><<<gblocks, 256, 0, stream>>>(x, nullptr, Mfh, Mfl, c1c2, degI, n, pre, Vh);
    else
      gemm_kernel<1><<<gblocks, 256, 0, stream>>>(pre, scsh + (l-1)*2*H, Mfh + l*mstride, Mfl + l*mstride,
                                                  c1c2 + l*2*H, degI, n, pre, Vh);
    agg_kernel<<<nagg, 256, 0, stream>>>(rowptr, csr_src, Vh, pre, n, partial);
    redstats_kernel<<<64, 256, 0, stream>>>(partial, nagg, bnsum + l*2*H,
                                            gamma + l*H, beta + l*H, 1.f/(float)n,
                                            scsh + l*2*H, cnt + l);
  }
  head_kernel<<<B, 256, 0, stream>>>(pre, scsh + 2*2*H, gofs, Wf1, bf1, Wf2, bf2, Wf3, bf3, out);
}

// Round 14
// 397.009 us; speedup vs baseline: 1.2928x; 1.2928x over previous
//
#include <hip/hip_runtime.h>
#include <hip/hip_fp16.h>

#define H 128
#define NEG 0.2f
#define EPSBN 1e-5f
#define BM 32

__device__ __forceinline__ float lrelu(float v){ return v >= 0.f ? v : NEG*v; }

union HU { __half2 h; unsigned int u; };

typedef __attribute__((ext_vector_type(8))) short bf16x8;
typedef __attribute__((ext_vector_type(4))) float f32x4;
#define MFMA16(a,b,c) __builtin_amdgcn_mfma_f32_16x16x32_bf16(a,b,c,0,0,0)

__device__ __forceinline__ unsigned short bf16_rn(float x){
  unsigned int u = __float_as_uint(x);
  u += 0x7fffu + ((u >> 16) & 1u);
  return (unsigned short)(u >> 16);
}
__device__ __forceinline__ float bf16f(unsigned short h){
  return __uint_as_float(((unsigned int)h) << 16);
}

__device__ __forceinline__ void asplit(const float* As, int aofs, bf16x8& ah, bf16x8& al){
  float av[8];
  *reinterpret_cast<float4*>(&av[0]) = *reinterpret_cast<const float4*>(&As[aofs]);
  *reinterpret_cast<float4*>(&av[4]) = *reinterpret_cast<const float4*>(&As[aofs+4]);
  #pragma unroll
  for (int j=0;j<8;j++){
    unsigned short h = bf16_rn(av[j]);
    ah[j] = (short)h;
    al[j] = (short)bf16_rn(av[j] - bf16f(h));
  }
}

// ---------- prep: N1|N2 = [We_top; We_bot] @ Wl  (per layer) ----------
__global__ void prep1_kernel(const float* __restrict__ We, const float* __restrict__ Wl,
                             float* __restrict__ Ntmp){
  int l = blockIdx.x >> 7;
  int k = blockIdx.x & 127;
  int j = threadIdx.x;          // 0..255
  __shared__ float WeS[2*H];
  if (j < H) WeS[j] = We[(size_t)(l*2*H + k)*H + j];
  else       WeS[j] = We[(size_t)(l*2*H + 128 + k)*H + (j-128)];
  __syncthreads();
  const float* wl = Wl + (size_t)l*H*H;
  int sel = (j >> 7) << 7;      // 0 or 128
  int jj = j & 127;
  float acc = 0.f;
  #pragma unroll 8
  for (int m=0;m<H;m++) acc += WeS[sel + m] * wl[m*H + jj];
  Ntmp[(size_t)(l*H + k)*256 + j] = acc;
}

// ---------- prep: Mcomb = Wg @ [N1|N2] ----------
__global__ void prep2_kernel(const float* __restrict__ Wg, const float* __restrict__ Ntmp,
                             float* __restrict__ Mcomb){
  int l = blockIdx.x >> 7;
  int k = blockIdx.x & 127;
  int j = threadIdx.x;          // 0..255
  __shared__ float WgS[H];
  if (j < H) WgS[j] = Wg[(size_t)(l*H + k)*H + j];
  __syncthreads();
  const float* nt = Ntmp + (size_t)l*H*256;
  float acc = 0.f;
  #pragma unroll 8
  for (int m=0;m<H;m++) acc += WgS[m] * nt[m*256 + j];
  Mcomb[(size_t)(l*H + k)*256 + j] = acc;
}

// ---------- prep: split Mcomb -> bf16 hi/lo in MFMA fragment order ----------
// layout: [l][ks][ct][lane][j]  (ks: K/32, ct: col-tile/16, lane 0..63, j 0..7)
__global__ void prep3_kernel(const float* __restrict__ Mcomb,
                             unsigned short* __restrict__ Mfh, unsigned short* __restrict__ Mfl){
  int bid = blockIdx.x;             // l*64 + ks*16 + ct
  int l  = bid >> 6;
  int ks = (bid >> 4) & 3;
  int ct = bid & 15;
  int lane = threadIdx.x;           // 0..63
  const float* M = Mcomb + (size_t)l*H*256;
  size_t base = ((((size_t)l*4 + ks)*16 + ct)*64 + lane)*8;
  int col = ct*16 + (lane & 15);
  int g = lane >> 4;
  #pragma unroll
  for (int j=0;j<8;j++){
    int k = ks*32 + 8*g + j;
    float v = M[(size_t)k*256 + col];
    unsigned short hi = bf16_rn(v);
    unsigned short lo = bf16_rn(v - bf16f(hi));
    Mfh[base + j] = hi;
    Mfl[base + j] = lo;
  }
}

// ---------- prep: c1 = be@Wl ; c2 = bg@Wl + bl ----------
__global__ void prepc_kernel(const float* __restrict__ be, const float* __restrict__ bg,
                             const float* __restrict__ bl, const float* __restrict__ Wl,
                             float* __restrict__ c1c2){
  int l = blockIdx.x;
  int j = threadIdx.x;          // 0..127
  const float* wl = Wl + (size_t)l*H*H;
  float a1=0.f, a2=0.f;
  for (int m=0;m<H;m++){ float w = wl[m*H + j]; a1 += be[l*H+m]*w; a2 += bg[l*H+m]*w; }
  c1c2[l*2*H + j]     = a1;
  c1c2[l*2*H + H + j] = a2 + bl[l*H + j];
}

// ---------- in-degree count + per-edge rank (rank = order within destination) ----------
__global__ void deg_kernel(const int* __restrict__ ei, int E, int* __restrict__ degI,
                           unsigned short* __restrict__ rankA){
  int e = blockIdx.x*blockDim.x + threadIdx.x;
  if (e < E){
    int r = atomicAdd(&degI[ei[E + e]], 1);
    rankA[e] = (unsigned short)r;
  }
}

// ---------- CSR build: block-wise inclusive scan of degrees ----------
__global__ void scan1_kernel(const int* __restrict__ degI, int n,
                             int* __restrict__ incl, int* __restrict__ bsum){
  int i = blockIdx.x*256 + threadIdx.x;
  __shared__ int sh[256];
  int v = (i < n) ? degI[i] : 0;
  sh[threadIdx.x] = v;
  __syncthreads();
  for (int ofs=1; ofs<256; ofs<<=1){
    int t = (threadIdx.x >= ofs) ? sh[threadIdx.x - ofs] : 0;
    __syncthreads();
    sh[threadIdx.x] += t;
    __syncthreads();
  }
  if (i < n) incl[i] = sh[threadIdx.x];
  if (threadIdx.x == 255) bsum[blockIdx.x] = sh[255];
}

__global__ void scan2_kernel(int* __restrict__ bsum, int nb){
  __shared__ int sh[256];
  int v = (threadIdx.x < nb) ? bsum[threadIdx.x] : 0;
  sh[threadIdx.x] = v;
  __syncthreads();
  for (int ofs=1; ofs<256; ofs<<=1){
    int t = (threadIdx.x >= ofs) ? sh[threadIdx.x - ofs] : 0;
    __syncthreads();
    sh[threadIdx.x] += t;
    __syncthreads();
  }
  if (threadIdx.x < nb) bsum[threadIdx.x] = sh[threadIdx.x] - v;  // exclusive
}

__global__ void scan3_kernel(const int* __restrict__ incl, const int* __restrict__ degI,
                             const int* __restrict__ bexcl, int n, int E,
                             int* __restrict__ rowptr){
  int i = blockIdx.x*256 + threadIdx.x;
  if (i < n){
    int start = incl[i] - degI[i] + bexcl[blockIdx.x];
    rowptr[i] = start;
    if (i == n-1) rowptr[n] = E;
  }
}

// ---------- atomic-free fill: pos = rowptr[dst] + rank ----------
__global__ void fill_kernel(const int* __restrict__ ei, int E,
                            const int* __restrict__ rowptr, const unsigned short* __restrict__ rankA,
                            unsigned short* __restrict__ csr_src){
  int e = blockIdx.x*256 + threadIdx.x;
  if (e < E){
    int c = ei[E + e];
    int pos = rowptr[c] + (int)rankA[e];
    csr_src[pos] = (unsigned short)ei[e];
  }
}

// ---------- graph boundary offsets from sorted batch ----------
__global__ void gofs_kernel(const int* __restrict__ batch, int n, int B, int* __restrict__ gofs){
  int i = blockIdx.x*256 + threadIdx.x;
  if (i >= n) return;
  if (i == 0){
    int b0 = batch[0];
    for (int g=0; g<=b0; g++) gofs[g] = 0;
  } else {
    int bp = batch[i-1], bc = batch[i];
    for (int g=bp+1; g<=bc; g++) gofs[g] = i;
  }
  if (i == n-1){
    int bl = batch[n-1];
    for (int g=bl+1; g<=B; g++) gofs[g] = n;
  }
}

// ---------- MFMA GEMM: [U|V] = A @ M (128x256), split-bf16: U 3-term, V 2-term ----------
// BM=32, 256 thr = 4 waves (rowtile = w&1, colgroup = w>>1).
// Ping-pong named-register prefetch of next-ks B fragments (c* / n* sets).
#define KSBODY(KS, C, N, PREF) \
  { bf16x8 ah, al; asplit(As, arow_*132 + (KS)*32 + agrp, ah, al); \
    if (PREF){ int nb = fb + ((KS)+1)*1024; \
      N##U0h = Bh[nb];     N##U1h = Bh[nb+64];  N##U2h = Bh[nb+128]; N##U3h = Bh[nb+192]; \
      N##U0l = Bl[nb];     N##U1l = Bl[nb+64];  N##U2l = Bl[nb+128]; N##U3l = Bl[nb+192]; \
      N##V0h = Bh[nb+512]; N##V1h = Bh[nb+576]; N##V2h = Bh[nb+640]; N##V3h = Bh[nb+704]; } \
    accU[0]=MFMA16(ah,C##U0h,accU[0]); accU[0]=MFMA16(al,C##U0h,accU[0]); accU[0]=MFMA16(ah,C##U0l,accU[0]); \
    accV[0]=MFMA16(ah,C##V0h,accV[0]); accV[0]=MFMA16(al,C##V0h,accV[0]); \
    accU[1]=MFMA16(ah,C##U1h,accU[1]); accU[1]=MFMA16(al,C##U1h,accU[1]); accU[1]=MFMA16(ah,C##U1l,accU[1]); \
    accV[1]=MFMA16(ah,C##V1h,accV[1]); accV[1]=MFMA16(al,C##V1h,accV[1]); \
    accU[2]=MFMA16(ah,C##U2h,accU[2]); accU[2]=MFMA16(al,C##U2h,accU[2]); accU[2]=MFMA16(ah,C##U2l,accU[2]); \
    accV[2]=MFMA16(ah,C##V2h,accV[2]); accV[2]=MFMA16(al,C##V2h,accV[2]); \
    accU[3]=MFMA16(ah,C##U3h,accU[3]); accU[3]=MFMA16(al,C##U3h,accU[3]); accU[3]=MFMA16(ah,C##U3l,accU[3]); \
    accV[3]=MFMA16(ah,C##V3h,accV[3]); accV[3]=MFMA16(al,C##V3h,accV[3]); }

template<int XF>
__global__ __launch_bounds__(256)
void gemm_kernel(const float* __restrict__ Zin, const float* __restrict__ bnp,
                 const unsigned short* __restrict__ Mfh, const unsigned short* __restrict__ Mfl,
                 const float* __restrict__ c1c2, const int* __restrict__ degI,
                 int n, float* __restrict__ pre, __half* __restrict__ Vh){
  __shared__ float As[32*132];      // [row][k] padded to 132
  int brow = blockIdx.x * BM;
  int t = threadIdx.x;

  int lane = t & 63;
  int w = t >> 6;
  int rowtile = w & 1, colgroup = w >> 1;
  const bf16x8* Bh = reinterpret_cast<const bf16x8*>(Mfh);
  const bf16x8* Bl = reinterpret_cast<const bf16x8*>(Mfl);
  int fb = colgroup*4*64 + lane;    // frag index (ks=0, ct=colgroup*4)

  // ---- issue ks0 B loads early (overlap with A staging) ----
  bf16x8 cU0h,cU1h,cU2h,cU3h, cU0l,cU1l,cU2l,cU3l, cV0h,cV1h,cV2h,cV3h;
  bf16x8 nU0h,nU1h,nU2h,nU3h, nU0l,nU1l,nU2l,nU3l, nV0h,nV1h,nV2h,nV3h;
  cU0h = Bh[fb];     cU1h = Bh[fb+64];  cU2h = Bh[fb+128]; cU3h = Bh[fb+192];
  cU0l = Bl[fb];     cU1l = Bl[fb+64];  cU2l = Bl[fb+128]; cU3l = Bl[fb+192];
  cV0h = Bh[fb+512]; cV1h = Bh[fb+576]; cV2h = Bh[fb+640]; cV3h = Bh[fb+704];

  // ---- stage A (all K) into LDS ----
  {
    int srow = t >> 3, sf = t & 7;
    int gr = brow + srow;
    bool act = (gr < n);
    const float* zrow = Zin + (size_t)gr*H;
    #pragma unroll
    for (int u=0; u<4; u++){
      int c4 = sf + 8*u;            // float4 index 0..31
      float4 g = make_float4(0.f,0.f,0.f,0.f);
      if (act) g = *reinterpret_cast<const float4*>(&zrow[c4*4]);
      if (XF){
        float4 sc4 = *reinterpret_cast<const float4*>(&bnp[c4*4]);
        float4 sh4 = *reinterpret_cast<const float4*>(&bnp[H + c4*4]);
        g.x = lrelu(g.x)*sc4.x + sh4.x;
        g.y = lrelu(g.y)*sc4.y + sh4.y;
        g.z = lrelu(g.z)*sc4.z + sh4.z;
        g.w = lrelu(g.w)*sc4.w + sh4.w;
      }
      *reinterpret_cast<float4*>(&As[srow*132 + c4*4]) = g;
    }
  }
  __syncthreads();

  f32x4 accU[4], accV[4];
  #pragma unroll
  for (int i=0;i<4;i++){
    accU[i] = (f32x4){0.f,0.f,0.f,0.f};
    accV[i] = (f32x4){0.f,0.f,0.f,0.f};
  }
  int arow_ = rowtile*16 + (lane & 15);
  int agrp  = (lane >> 4) << 3;     // 8*(lane>>4)

  KSBODY(0, c, n, 1)
  KSBODY(1, n, c, 1)
  KSBODY(2, c, n, 1)
  KSBODY(3, n, c, 0)

  // ---- epilogue: C/D layout col = lane&15, row = (lane>>4)*4 + reg ----
  int rowbase = brow + rowtile*16 + ((lane >> 4) << 2);
  float dg[4];
  #pragma unroll
  for (int r=0;r<4;r++){
    int gr = rowbase + r;
    dg[r] = (gr < n) ? (float)(degI[gr] + 1) : 0.f;
  }
  #pragma unroll
  for (int ctu=0; ctu<4; ctu++){
    int colU = colgroup*64 + ctu*16 + (lane & 15);
    float c1v = c1c2[colU], c2v = c1c2[H + colU];
    #pragma unroll
    for (int r=0;r<4;r++){
      int gr = rowbase + r;
      if (gr < n){
        float uu = accU[ctu][r], vv = accV[ctu][r];
        pre[(size_t)gr*H + colU] = dg[r]*(uu + c1v) + c2v + vv;
        Vh [(size_t)gr*H + colU] = __float2half(vv);
      }
    }
  }
}

// ---------- CSR aggregation + fused BN-stats partials (8-deep gather unroll) ----------
__global__ __launch_bounds__(256)
void agg_kernel(const int* __restrict__ rowptr, const unsigned short* __restrict__ csr_src,
                const __half* __restrict__ Vh, float* __restrict__ pre, int n,
                float* __restrict__ partial){
  int node = blockIdx.x*8 + (threadIdx.x >> 5);
  int lane = threadIdx.x & 31;
  float4 h4 = make_float4(0.f,0.f,0.f,0.f);
  float4 q4 = make_float4(0.f,0.f,0.f,0.f);
  if (node < n){
    int p  = rowptr[node];
    int pe = rowptr[node+1];
    const __half* Vb = Vh + lane*4;
    float4 a = make_float4(0.f,0.f,0.f,0.f);
    for (; p+8 <= pe; p+=8){
      int s0 = csr_src[p],   s1 = csr_src[p+1], s2 = csr_src[p+2], s3 = csr_src[p+3];
      int s4 = csr_src[p+4], s5 = csr_src[p+5], s6 = csr_src[p+6], s7 = csr_src[p+7];
      uint2 r0 = *reinterpret_cast<const uint2*>(&Vb[(size_t)s0*H]);
      uint2 r1 = *reinterpret_cast<const uint2*>(&Vb[(size_t)s1*H]);
      uint2 r2 = *reinterpret_cast<const uint2*>(&Vb[(size_t)s2*H]);
      uint2 r3 = *reinterpret_cast<const uint2*>(&Vb[(size_t)s3*H]);
      uint2 r4 = *reinterpret_cast<const uint2*>(&Vb[(size_t)s4*H]);
      uint2 r5 = *reinterpret_cast<const uint2*>(&Vb[(size_t)s5*H]);
      uint2 r6 = *reinterpret_cast<const uint2*>(&Vb[(size_t)s6*H]);
      uint2 r7 = *reinterpret_cast<const uint2*>(&Vb[(size_t)s7*H]);
      HU ua, ub;
      float2 fa, fb;
      ua.u=r0.x; ub.u=r0.y; fa=__half22float2(ua.h); fb=__half22float2(ub.h);
      a.x+=fa.x; a.y+=fa.y; a.z+=fb.x; a.w+=fb.y;
      ua.u=r1.x; ub.u=r1.y; fa=__half22float2(ua.h); fb=__half22float2(ub.h);
      a.x+=fa.x; a.y+=fa.y; a.z+=fb.x; a.w+=fb.y;
      ua.u=r2.x; ub.u=r2.y; fa=__half22float2(ua.h); fb=__half22float2(ub.h);
      a.x+=fa.x; a.y+=fa.y; a.z+=fb.x; a.w+=fb.y;
      ua.u=r3.x; ub.u=r3.y; fa=__half22float2(ua.h); fb=__half22float2(ub.h);
      a.x+=fa.x; a.y+=fa.y; a.z+=fb.x; a.w+=fb.y;
      ua.u=r4.x; ub.u=r4.y; fa=__half22float2(ua.h); fb=__half22float2(ub.h);
      a.x+=fa.x; a.y+=fa.y; a.z+=fb.x; a.w+=fb.y;
      ua.u=r5.x; ub.u=r5.y; fa=__half22float2(ua.h); fb=__half22float2(ub.h);
      a.x+=fa.x; a.y+=fa.y; a.z+=fb.x; a.w+=fb.y;
      ua.u=r6.x; ub.u=r6.y; fa=__half22float2(ua.h); fb=__half22float2(ub.h);
      a.x+=fa.x; a.y+=fa.y; a.z+=fb.x; a.w+=fb.y;
      ua.u=r7.x; ub.u=r7.y; fa=__half22float2(ua.h); fb=__half22float2(ub.h);
      a.x+=fa.x; a.y+=fa.y; a.z+=fb.x; a.w+=fb.y;
    }
    for (; p+2 <= pe; p+=2){
      int s0 = csr_src[p], s1 = csr_src[p+1];
      uint2 r0 = *reinterpret_cast<const uint2*>(&Vb[(size_t)s0*H]);
      uint2 r1 = *reinterpret_cast<const uint2*>(&Vb[(size_t)s1*H]);
      HU ua, ub;
      float2 fa, fb;
      ua.u=r0.x; ub.u=r0.y; fa=__half22float2(ua.h); fb=__half22float2(ub.h);
      a.x+=fa.x; a.y+=fa.y; a.z+=fb.x; a.w+=fb.y;
      ua.u=r1.x; ub.u=r1.y; fa=__half22float2(ua.h); fb=__half22float2(ub.h);
      a.x+=fa.x; a.y+=fa.y; a.z+=fb.x; a.w+=fb.y;
    }
    for (; p < pe; p++){
      int s = csr_src[p];
      uint2 r = *reinterpret_cast<const uint2*>(&Vb[(size_t)s*H]);
      HU ua, ub; ua.u = r.x; ub.u = r.y;
      float2 fa = __half22float2(ua.h), fb = __half22float2(ub.h);
      a.x += fa.x; a.y += fa.y; a.z += fb.x; a.w += fb.y;
    }
    float4* pp = reinterpret_cast<float4*>(&pre[(size_t)node*H + lane*4]);
    float4 pr = *pp;
    pr.x += a.x; pr.y += a.y; pr.z += a.z; pr.w += a.w;
    *pp = pr;
    h4.x = lrelu(pr.x); h4.y = lrelu(pr.y); h4.z = lrelu(pr.z); h4.w = lrelu(pr.w);
    q4.x = h4.x*h4.x;   q4.y = h4.y*h4.y;   q4.z = h4.z*h4.z;   q4.w = h4.w*h4.w;
  }
  __shared__ float4 red[8][32];
  int slot = threadIdx.x >> 5;
  red[slot][lane] = h4;
  __syncthreads();
  if (threadIdx.x < 32){
    float4 tt = red[0][threadIdx.x];
    #pragma unroll
    for (int r=1;r<8;r++){
      float4 v = red[r][threadIdx.x];
      tt.x += v.x; tt.y += v.y; tt.z += v.z; tt.w += v.w;
    }
    *reinterpret_cast<float4*>(&partial[(size_t)blockIdx.x*256 + threadIdx.x*4]) = tt;
  }
  __syncthreads();
  red[slot][lane] = q4;
  __syncthreads();
  if (threadIdx.x < 32){
    float4 tt = red[0][threadIdx.x];
    #pragma unroll
    for (int r=1;r<8;r++){
      float4 v = red[r][threadIdx.x];
      tt.x += v.x; tt.y += v.y; tt.z += v.z; tt.w += v.w;
    }
    *reinterpret_cast<float4*>(&partial[(size_t)blockIdx.x*256 + 128 + threadIdx.x*4]) = tt;
  }
}

// ---------- reduce partials -> bnsum[256]; last block finalizes scsh ----------
__global__ __launch_bounds__(256)
void redstats_kernel(const float* __restrict__ partial, int nb, float* __restrict__ bnsum,
                     const float* __restrict__ gamma, const float* __restrict__ beta,
                     float inv_n, float* __restrict__ scsh, int* __restrict__ cnt){
  int c = threadIdx.x;
  float acc = 0.f;
  for (int b = blockIdx.x; b < nb; b += 64)
    acc += partial[(size_t)b*256 + c];
  atomicAdd(&bnsum[c], acc);
  __threadfence();
  __shared__ int lastS;
  __syncthreads();
  if (threadIdx.x == 0){
    int prev = atomicAdd(cnt, 1);
    lastS = (prev == 63) ? 1 : 0;
  }
  __syncthreads();
  if (lastS && c < H){
    float s  = atomicAdd(&bnsum[c], 0.f);       // device-coherent read
    float ss = atomicAdd(&bnsum[H + c], 0.f);
    float mu  = s * inv_n;
    float var = ss * inv_n - mu*mu;
    float rs  = rsqrtf(fmaxf(var, 0.f) + EPSBN);
    float sc  = gamma[c] * rs;
    scsh[c]     = sc;
    scsh[H + c] = beta[c] - mu*sc;
  }
}

// ---------- pooled segment-sum of z2 = lrelu(pre2)*sc+sh (8 blocks/graph) ----------
__global__ __launch_bounds__(256)
void pool_kernel(const float* __restrict__ pre, const float* __restrict__ scsh,
                 const int* __restrict__ gofs, float* __restrict__ pooled){
  int g    = blockIdx.x >> 3;
  int part = blockIdx.x & 7;
  int col  = threadIdx.x & 127;
  int half = threadIdx.x >> 7;
  int s = gofs[g], e = gofs[g+1];
  float sc = scsh[col], sh = scsh[H + col];
  float acc = 0.f;
  for (int r = s + part*2 + half; r < e; r += 16)
    acc += lrelu(pre[(size_t)r*H + col])*sc + sh;
  if (acc != 0.f || part == 0)
    atomicAdd(&pooled[(size_t)g*H + col], acc);
}

// ---------- final MLP head: one block per graph ----------
__global__ __launch_bounds__(128)
void head_kernel(const float* __restrict__ pooled, const int* __restrict__ gofs,
                 const float* __restrict__ Wf1, const float* __restrict__ bf1,
                 const float* __restrict__ Wf2, const float* __restrict__ bf2,
                 const float* __restrict__ Wf3, const float* __restrict__ bf3,
                 float* __restrict__ out){
  int g = blockIdx.x;
  int c = threadIdx.x;
  __shared__ float pm[128], h1[128], h2[64];
  float cf = fmaxf((float)(gofs[g+1] - gofs[g]), 1.f);
  pm[c] = pooled[(size_t)g*H + c] / cf;
  __syncthreads();
  float a = bf1[c];
  for (int k=0;k<H;k++) a += pm[k]*Wf1[k*H + c];
  h1[c] = lrelu(a);
  __syncthreads();
  if (c < 64){
    float b = bf2[c];
    for (int k=0;k<H;k++) b += h1[k]*Wf2[k*64 + c];
    h2[c] = lrelu(b);
  }
  __syncthreads();
  if (c < 2){
    float o = bf3[c];
    for (int k=0;k<64;k++) o += h2[k]*Wf3[k*2 + c];
    out[g*2 + c] = o;
  }
}

extern "C" void kernel_launch(void* const* d_in, const int* in_sizes, int n_in,
                              void* d_out, int out_size, void* d_ws, size_t ws_size,
                              hipStream_t stream){
  const float* x     = (const float*)d_in[0];
  const int*   ei    = (const int*)d_in[1];
  const int*   batch = (const int*)d_in[3];
  const float* Wg    = (const float*)d_in[4];
  const float* bg    = (const float*)d_in[5];
  const float* We    = (const float*)d_in[6];
  const float* be    = (const float*)d_in[7];
  const float* Wl    = (const float*)d_in[8];
  const float* bl    = (const float*)d_in[9];
  const float* gamma = (const float*)d_in[10];
  const float* beta  = (const float*)d_in[11];
  const float* Wf1   = (const float*)d_in[12];
  const float* bf1   = (const float*)d_in[13];
  const float* Wf2   = (const float*)d_in[14];
  const float* bf2   = (const float*)d_in[15];
  const float* Wf3   = (const float*)d_in[16];
  const float* bf3   = (const float*)d_in[17];
  float* out = (float*)d_out;

  int n = in_sizes[0] / H;   // 50000
  int E = in_sizes[1] / 2;   // 800000
  int B = out_size / 2;      // 50

  int nagg = (n + 7)/8;      // agg/partial blocks

  char* ws = (char*)d_ws;
  size_t off = 0;
  auto alloc = [&](size_t bytes)->void*{ void* p = ws + off; off += (bytes + 255) & ~255ULL; return p; };
  float*  pre    = (float*)alloc((size_t)n*H*4);
  __half* Vh     = (__half*)alloc((size_t)n*H*2);
  float*  Mcomb  = (float*)alloc((size_t)3*H*256*4);
  float*  Ntmp   = (float*)alloc((size_t)3*H*256*4);
  unsigned short* Mfh = (unsigned short*)alloc((size_t)3*4*16*64*8*2);
  unsigned short* Mfl = (unsigned short*)alloc((size_t)3*4*16*64*8*2);
  float*  c1c2   = (float*)alloc(3*2*H*4);
  float*  scsh   = (float*)alloc(3*2*H*4);
  int*    incl   = (int*)alloc((size_t)n*4);
  int*    bsum   = (int*)alloc(256*4);
  int*    rowptr = (int*)alloc((size_t)(n+1)*4);
  unsigned short* rankA   = (unsigned short*)alloc((size_t)E*2);
  unsigned short* csr_src = (unsigned short*)alloc((size_t)E*2);
  int*    gofs   = (int*)alloc((size_t)(B+1)*4);
  float*  partial= (float*)alloc((size_t)nagg*256*4);
  char* zbase = ws + off;                 // ---- zeroed region starts ----
  float* bnsum  = (float*)alloc(3*2*H*4);
  int*   cnt    = (int*)alloc(3*4);
  int*   degI   = (int*)alloc((size_t)n*4);
  float* pooled = (float*)alloc((size_t)B*H*4);
  size_t zbytes = (size_t)((ws + off) - zbase);
  hipMemsetAsync(zbase, 0, zbytes, stream);

  prep1_kernel<<<3*H, 256, 0, stream>>>(We, Wl, Ntmp);
  prep2_kernel<<<3*H, 256, 0, stream>>>(Wg, Ntmp, Mcomb);
  prep3_kernel<<<3*64, 64, 0, stream>>>(Mcomb, Mfh, Mfl);
  prepc_kernel<<<3, 128, 0, stream>>>(be, bg, bl, Wl, c1c2);
  deg_kernel<<<(E+255)/256, 256, 0, stream>>>(ei, E, degI, rankA);

  int nb = (n + 255)/256;
  scan1_kernel<<<nb, 256, 0, stream>>>(degI, n, incl, bsum);
  scan2_kernel<<<1, 256, 0, stream>>>(bsum, nb);
  scan3_kernel<<<nb, 256, 0, stream>>>(incl, degI, bsum, n, E, rowptr);
  fill_kernel<<<(E+255)/256, 256, 0, stream>>>(ei, E, rowptr, rankA, csr_src);
  gofs_kernel<<<nb, 256, 0, stream>>>(batch, n, B, gofs);

  int gblocks = (n + BM - 1)/BM;
  size_t mstride = (size_t)4*16*64*8;   // shorts per layer
  for (int l=0; l<3; l++){
    if (l == 0)
      gemm_kernel<0><<<gblocks, 256, 0, stream>>>(x, nullptr, Mfh, Mfl, c1c2, degI, n, pre, Vh);
    else
      gemm_kernel<1><<<gblocks, 256, 0, stream>>>(pre, scsh + (l-1)*2*H, Mfh + l*mstride, Mfl + l*mstride,
                                                  c1c2 + l*2*H, degI, n, pre, Vh);
    agg_kernel<<<nagg, 256, 0, stream>>>(rowptr, csr_src, Vh, pre, n, partial);
    redstats_kernel<<<64, 256, 0, stream>>>(partial, nagg, bnsum + l*2*H,
                                            gamma + l*H, beta + l*H, 1.f/(float)n,
                                            scsh + l*2*H, cnt + l);
  }
  pool_kernel<<<B*8, 256, 0, stream>>>(pre, scsh + 2*2*H, gofs, pooled);
  head_kernel<<<B, 128, 0, stream>>>(pooled, gofs, Wf1, bf1, Wf2, bf2, Wf3, bf3, out);
}

// Round 15
// 391.356 us; speedup vs baseline: 1.3115x; 1.0144x over previous
//
#include <hip/hip_runtime.h>
#include <hip/hip_fp16.h>

#define H 128
#define NEG 0.2f
#define EPSBN 1e-5f
#define BM 32

__device__ __forceinline__ float lrelu(float v){ return v >= 0.f ? v : NEG*v; }

union HU { __half2 h; unsigned int u; };

typedef __attribute__((ext_vector_type(8))) short bf16x8;
typedef __attribute__((ext_vector_type(4))) float f32x4;
#define MFMA16(a,b,c) __builtin_amdgcn_mfma_f32_16x16x32_bf16(a,b,c,0,0,0)

__device__ __forceinline__ unsigned short bf16_rn(float x){
  unsigned int u = __float_as_uint(x);
  u += 0x7fffu + ((u >> 16) & 1u);
  return (unsigned short)(u >> 16);
}
__device__ __forceinline__ float bf16f(unsigned short h){
  return __uint_as_float(((unsigned int)h) << 16);
}

__device__ __forceinline__ void asplit(const float* As, int aofs, bf16x8& ah, bf16x8& al){
  float av[8];
  *reinterpret_cast<float4*>(&av[0]) = *reinterpret_cast<const float4*>(&As[aofs]);
  *reinterpret_cast<float4*>(&av[4]) = *reinterpret_cast<const float4*>(&As[aofs+4]);
  #pragma unroll
  for (int j=0;j<8;j++){
    unsigned short h = bf16_rn(av[j]);
    ah[j] = (short)h;
    al[j] = (short)bf16_rn(av[j] - bf16f(h));
  }
}

// ================= K1: prep1 | prepc | deg | gofs (all independent) =================
__global__ __launch_bounds__(256)
void k1_kernel(const float* __restrict__ We, const float* __restrict__ Wl,
               float* __restrict__ Ntmp,
               const float* __restrict__ be, const float* __restrict__ bg,
               const float* __restrict__ bl, float* __restrict__ c1c2,
               const int* __restrict__ ei, int E, int* __restrict__ degI,
               unsigned short* __restrict__ rankA,
               const int* __restrict__ batch, int n, int B, int* __restrict__ gofs,
               int nbDeg){
  int b = blockIdx.x;
  int t = threadIdx.x;
  if (b < 3*H){
    // ---- prep1: N1|N2 = [We_top; We_bot] @ Wl ----
    int l = b >> 7;
    int k = b & 127;
    __shared__ float WeS[2*H];
    if (t < H) WeS[t] = We[(size_t)(l*2*H + k)*H + t];
    else       WeS[t] = We[(size_t)(l*2*H + 128 + k)*H + (t-128)];
    __syncthreads();
    const float* wl = Wl + (size_t)l*H*H;
    int sel = (t >> 7) << 7;
    int jj = t & 127;
    float acc = 0.f;
    #pragma unroll 8
    for (int m=0;m<H;m++) acc += WeS[sel + m] * wl[m*H + jj];
    Ntmp[(size_t)(l*H + k)*256 + t] = acc;
  } else if (b < 3*H + 3){
    // ---- prepc: c1 = be@Wl ; c2 = bg@Wl + bl ----
    int l = b - 3*H;
    if (t < H){
      const float* wl = Wl + (size_t)l*H*H;
      float a1=0.f, a2=0.f;
      for (int m=0;m<H;m++){ float w = wl[m*H + t]; a1 += be[l*H+m]*w; a2 += bg[l*H+m]*w; }
      c1c2[l*2*H + t]     = a1;
      c1c2[l*2*H + H + t] = a2 + bl[l*H + t];
    }
  } else if (b < 3*H + 3 + nbDeg){
    // ---- deg: in-degree count + per-edge rank ----
    int e = (b - 3*H - 3)*256 + t;
    if (e < E){
      int r = atomicAdd(&degI[ei[E + e]], 1);
      rankA[e] = (unsigned short)r;
    }
  } else {
    // ---- gofs: graph boundary offsets from sorted batch ----
    int i = (b - 3*H - 3 - nbDeg)*256 + t;
    if (i >= n) return;
    if (i == 0){
      int b0 = batch[0];
      for (int g=0; g<=b0; g++) gofs[g] = 0;
    } else {
      int bp = batch[i-1], bc = batch[i];
      for (int g=bp+1; g<=bc; g++) gofs[g] = i;
    }
    if (i == n-1){
      int bl2 = batch[n-1];
      for (int g=bl2+1; g<=B; g++) gofs[g] = n;
    }
  }
}

// ================= K2: prep2 | scan1 =================
__global__ __launch_bounds__(256)
void k2_kernel(const float* __restrict__ Wg, const float* __restrict__ Ntmp,
               float* __restrict__ Mcomb,
               const int* __restrict__ degI, int n,
               int* __restrict__ incl, int* __restrict__ bsum){
  int b = blockIdx.x;
  int t = threadIdx.x;
  if (b < 3*H){
    // ---- prep2: Mcomb = Wg @ [N1|N2] ----
    int l = b >> 7;
    int k = b & 127;
    __shared__ float WgS[H];
    if (t < H) WgS[t] = Wg[(size_t)(l*H + k)*H + t];
    __syncthreads();
    const float* nt = Ntmp + (size_t)l*H*256;
    float acc = 0.f;
    #pragma unroll 8
    for (int m=0;m<H;m++) acc += WgS[m] * nt[m*256 + t];
    Mcomb[(size_t)(l*H + k)*256 + t] = acc;
  } else {
    // ---- scan1: block-wise inclusive scan of degrees ----
    int vb = b - 3*H;
    int i = vb*256 + t;
    __shared__ int sh[256];
    int v = (i < n) ? degI[i] : 0;
    sh[t] = v;
    __syncthreads();
    for (int ofs=1; ofs<256; ofs<<=1){
      int tv = (t >= ofs) ? sh[t - ofs] : 0;
      __syncthreads();
      sh[t] += tv;
      __syncthreads();
    }
    if (i < n) incl[i] = sh[t];
    if (t == 255) bsum[vb] = sh[255];
  }
}

// ================= K3: prep3 | scan2 =================
__global__ __launch_bounds__(256)
void k3_kernel(const float* __restrict__ Mcomb,
               unsigned short* __restrict__ Mfh, unsigned short* __restrict__ Mfl,
               int* __restrict__ bsum, int nb){
  int b = blockIdx.x;
  int t = threadIdx.x;
  if (b < 3*64){
    // ---- prep3: split Mcomb -> bf16 hi/lo in MFMA fragment order ----
    if (t >= 64) return;
    int l  = b >> 6;
    int ks = (b >> 4) & 3;
    int ct = b & 15;
    int lane = t;
    const float* M = Mcomb + (size_t)l*H*256;
    size_t base = ((((size_t)l*4 + ks)*16 + ct)*64 + lane)*8;
    int col = ct*16 + (lane & 15);
    int g = lane >> 4;
    #pragma unroll
    for (int j=0;j<8;j++){
      int k = ks*32 + 8*g + j;
      float v = M[(size_t)k*256 + col];
      unsigned short hi = bf16_rn(v);
      unsigned short lo = bf16_rn(v - bf16f(hi));
      Mfh[base + j] = hi;
      Mfl[base + j] = lo;
    }
  } else {
    // ---- scan2: exclusive scan of block sums ----
    __shared__ int sh[256];
    int v = (t < nb) ? bsum[t] : 0;
    sh[t] = v;
    __syncthreads();
    for (int ofs=1; ofs<256; ofs<<=1){
      int tv = (t >= ofs) ? sh[t - ofs] : 0;
      __syncthreads();
      sh[t] += tv;
      __syncthreads();
    }
    if (t < nb) bsum[t] = sh[t] - v;  // exclusive
  }
}

// ---------- scan3: rowptr ----------
__global__ void scan3_kernel(const int* __restrict__ incl, const int* __restrict__ degI,
                             const int* __restrict__ bexcl, int n, int E,
                             int* __restrict__ rowptr){
  int i = blockIdx.x*256 + threadIdx.x;
  if (i < n){
    int start = incl[i] - degI[i] + bexcl[blockIdx.x];
    rowptr[i] = start;
    if (i == n-1) rowptr[n] = E;
  }
}

// ---------- atomic-free fill: pos = rowptr[dst] + rank ----------
__global__ void fill_kernel(const int* __restrict__ ei, int E,
                            const int* __restrict__ rowptr, const unsigned short* __restrict__ rankA,
                            unsigned short* __restrict__ csr_src){
  int e = blockIdx.x*256 + threadIdx.x;
  if (e < E){
    int c = ei[E + e];
    int pos = rowptr[c] + (int)rankA[e];
    csr_src[pos] = (unsigned short)ei[e];
  }
}

// ---------- MFMA GEMM: [U|V] = A @ M (128x256), split-bf16: U 3-term, V 2-term ----------
#define KSBODY(KS, C, N, PREF) \
  { bf16x8 ah, al; asplit(As, arow_*132 + (KS)*32 + agrp, ah, al); \
    if (PREF){ int nb = fb + ((KS)+1)*1024; \
      N##U0h = Bh[nb];     N##U1h = Bh[nb+64];  N##U2h = Bh[nb+128]; N##U3h = Bh[nb+192]; \
      N##U0l = Bl[nb];     N##U1l = Bl[nb+64];  N##U2l = Bl[nb+128]; N##U3l = Bl[nb+192]; \
      N##V0h = Bh[nb+512]; N##V1h = Bh[nb+576]; N##V2h = Bh[nb+640]; N##V3h = Bh[nb+704]; } \
    accU[0]=MFMA16(ah,C##U0h,accU[0]); accU[0]=MFMA16(al,C##U0h,accU[0]); accU[0]=MFMA16(ah,C##U0l,accU[0]); \
    accV[0]=MFMA16(ah,C##V0h,accV[0]); accV[0]=MFMA16(al,C##V0h,accV[0]); \
    accU[1]=MFMA16(ah,C##U1h,accU[1]); accU[1]=MFMA16(al,C##U1h,accU[1]); accU[1]=MFMA16(ah,C##U1l,accU[1]); \
    accV[1]=MFMA16(ah,C##V1h,accV[1]); accV[1]=MFMA16(al,C##V1h,accV[1]); \
    accU[2]=MFMA16(ah,C##U2h,accU[2]); accU[2]=MFMA16(al,C##U2h,accU[2]); accU[2]=MFMA16(ah,C##U2l,accU[2]); \
    accV[2]=MFMA16(ah,C##V2h,accV[2]); accV[2]=MFMA16(al,C##V2h,accV[2]); \
    accU[3]=MFMA16(ah,C##U3h,accU[3]); accU[3]=MFMA16(al,C##U3h,accU[3]); accU[3]=MFMA16(ah,C##U3l,accU[3]); \
    accV[3]=MFMA16(ah,C##V3h,accV[3]); accV[3]=MFMA16(al,C##V3h,accV[3]); }

template<int XF>
__global__ __launch_bounds__(256)
void gemm_kernel(const float* __restrict__ Zin, const float* __restrict__ bnp,
                 const unsigned short* __restrict__ Mfh, const unsigned short* __restrict__ Mfl,
                 const float* __restrict__ c1c2, const int* __restrict__ degI,
                 int n, float* __restrict__ pre, __half* __restrict__ Vh){
  __shared__ float As[32*132];      // [row][k] padded to 132
  int brow = blockIdx.x * BM;
  int t = threadIdx.x;

  int lane = t & 63;
  int w = t >> 6;
  int rowtile = w & 1, colgroup = w >> 1;
  const bf16x8* Bh = reinterpret_cast<const bf16x8*>(Mfh);
  const bf16x8* Bl = reinterpret_cast<const bf16x8*>(Mfl);
  int fb = colgroup*4*64 + lane;    // frag index (ks=0, ct=colgroup*4)

  // ---- issue ks0 B loads early (overlap with A staging) ----
  bf16x8 cU0h,cU1h,cU2h,cU3h, cU0l,cU1l,cU2l,cU3l, cV0h,cV1h,cV2h,cV3h;
  bf16x8 nU0h,nU1h,nU2h,nU3h, nU0l,nU1l,nU2l,nU3l, nV0h,nV1h,nV2h,nV3h;
  cU0h = Bh[fb];     cU1h = Bh[fb+64];  cU2h = Bh[fb+128]; cU3h = Bh[fb+192];
  cU0l = Bl[fb];     cU1l = Bl[fb+64];  cU2l = Bl[fb+128]; cU3l = Bl[fb+192];
  cV0h = Bh[fb+512]; cV1h = Bh[fb+576]; cV2h = Bh[fb+640]; cV3h = Bh[fb+704];

  // ---- stage A (all K) into LDS ----
  {
    int srow = t >> 3, sf = t & 7;
    int gr = brow + srow;
    bool act = (gr < n);
    const float* zrow = Zin + (size_t)gr*H;
    #pragma unroll
    for (int u=0; u<4; u++){
      int c4 = sf + 8*u;            // float4 index 0..31
      float4 g = make_float4(0.f,0.f,0.f,0.f);
      if (act) g = *reinterpret_cast<const float4*>(&zrow[c4*4]);
      if (XF){
        float4 sc4 = *reinterpret_cast<const float4*>(&bnp[c4*4]);
        float4 sh4 = *reinterpret_cast<const float4*>(&bnp[H + c4*4]);
        g.x = lrelu(g.x)*sc4.x + sh4.x;
        g.y = lrelu(g.y)*sc4.y + sh4.y;
        g.z = lrelu(g.z)*sc4.z + sh4.z;
        g.w = lrelu(g.w)*sc4.w + sh4.w;
      }
      *reinterpret_cast<float4*>(&As[srow*132 + c4*4]) = g;
    }
  }
  __syncthreads();

  f32x4 accU[4], accV[4];
  #pragma unroll
  for (int i=0;i<4;i++){
    accU[i] = (f32x4){0.f,0.f,0.f,0.f};
    accV[i] = (f32x4){0.f,0.f,0.f,0.f};
  }
  int arow_ = rowtile*16 + (lane & 15);
  int agrp  = (lane >> 4) << 3;     // 8*(lane>>4)

  KSBODY(0, c, n, 1)
  KSBODY(1, n, c, 1)
  KSBODY(2, c, n, 1)
  KSBODY(3, n, c, 0)

  // ---- epilogue: C/D layout col = lane&15, row = (lane>>4)*4 + reg ----
  int rowbase = brow + rowtile*16 + ((lane >> 4) << 2);
  float dg[4];
  #pragma unroll
  for (int r=0;r<4;r++){
    int gr = rowbase + r;
    dg[r] = (gr < n) ? (float)(degI[gr] + 1) : 0.f;
  }
  #pragma unroll
  for (int ctu=0; ctu<4; ctu++){
    int colU = colgroup*64 + ctu*16 + (lane & 15);
    float c1v = c1c2[colU], c2v = c1c2[H + colU];
    #pragma unroll
    for (int r=0;r<4;r++){
      int gr = rowbase + r;
      if (gr < n){
        float uu = accU[ctu][r], vv = accV[ctu][r];
        pre[(size_t)gr*H + colU] = dg[r]*(uu + c1v) + c2v + vv;
        Vh [(size_t)gr*H + colU] = __float2half(vv);
      }
    }
  }
}

// ---------- CSR aggregation + fused BN-stats partials (8-deep gather unroll) ----------
// LAST=1: skip pre write-back, accumulate per-graph pooled sums of lrelu(pre)
template<int LAST>
__global__ __launch_bounds__(256)
void agg_kernel(const int* __restrict__ rowptr, const unsigned short* __restrict__ csr_src,
                const __half* __restrict__ Vh, float* __restrict__ pre, int n,
                float* __restrict__ partial,
                const int* __restrict__ batch, float* __restrict__ pooled){
  int node = blockIdx.x*8 + (threadIdx.x >> 5);
  int lane = threadIdx.x & 31;
  float4 h4 = make_float4(0.f,0.f,0.f,0.f);
  float4 q4 = make_float4(0.f,0.f,0.f,0.f);
  if (node < n){
    int p  = rowptr[node];
    int pe = rowptr[node+1];
    const __half* Vb = Vh + lane*4;
    float4 a = make_float4(0.f,0.f,0.f,0.f);
    for (; p+8 <= pe; p+=8){
      int s0 = csr_src[p],   s1 = csr_src[p+1], s2 = csr_src[p+2], s3 = csr_src[p+3];
      int s4 = csr_src[p+4], s5 = csr_src[p+5], s6 = csr_src[p+6], s7 = csr_src[p+7];
      uint2 r0 = *reinterpret_cast<const uint2*>(&Vb[(size_t)s0*H]);
      uint2 r1 = *reinterpret_cast<const uint2*>(&Vb[(size_t)s1*H]);
      uint2 r2 = *reinterpret_cast<const uint2*>(&Vb[(size_t)s2*H]);
      uint2 r3 = *reinterpret_cast<const uint2*>(&Vb[(size_t)s3*H]);
      uint2 r4 = *reinterpret_cast<const uint2*>(&Vb[(size_t)s4*H]);
      uint2 r5 = *reinterpret_cast<const uint2*>(&Vb[(size_t)s5*H]);
      uint2 r6 = *reinterpret_cast<const uint2*>(&Vb[(size_t)s6*H]);
      uint2 r7 = *reinterpret_cast<const uint2*>(&Vb[(size_t)s7*H]);
      HU ua, ub;
      float2 fa, fb;
      ua.u=r0.x; ub.u=r0.y; fa=__half22float2(ua.h); fb=__half22float2(ub.h);
      a.x+=fa.x; a.y+=fa.y; a.z+=fb.x; a.w+=fb.y;
      ua.u=r1.x; ub.u=r1.y; fa=__half22float2(ua.h); fb=__half22float2(ub.h);
      a.x+=fa.x; a.y+=fa.y; a.z+=fb.x; a.w+=fb.y;
      ua.u=r2.x; ub.u=r2.y; fa=__half22float2(ua.h); fb=__half22float2(ub.h);
      a.x+=fa.x; a.y+=fa.y; a.z+=fb.x; a.w+=fb.y;
      ua.u=r3.x; ub.u=r3.y; fa=__half22float2(ua.h); fb=__half22float2(ub.h);
      a.x+=fa.x; a.y+=fa.y; a.z+=fb.x; a.w+=fb.y;
      ua.u=r4.x; ub.u=r4.y; fa=__half22float2(ua.h); fb=__half22float2(ub.h);
      a.x+=fa.x; a.y+=fa.y; a.z+=fb.x; a.w+=fb.y;
      ua.u=r5.x; ub.u=r5.y; fa=__half22float2(ua.h); fb=__half22float2(ub.h);
      a.x+=fa.x; a.y+=fa.y; a.z+=fb.x; a.w+=fb.y;
      ua.u=r6.x; ub.u=r6.y; fa=__half22float2(ua.h); fb=__half22float2(ub.h);
      a.x+=fa.x; a.y+=fa.y; a.z+=fb.x; a.w+=fb.y;
      ua.u=r7.x; ub.u=r7.y; fa=__half22float2(ua.h); fb=__half22float2(ub.h);
      a.x+=fa.x; a.y+=fa.y; a.z+=fb.x; a.w+=fb.y;
    }
    for (; p+2 <= pe; p+=2){
      int s0 = csr_src[p], s1 = csr_src[p+1];
      uint2 r0 = *reinterpret_cast<const uint2*>(&Vb[(size_t)s0*H]);
      uint2 r1 = *reinterpret_cast<const uint2*>(&Vb[(size_t)s1*H]);
      HU ua, ub;
      float2 fa, fb;
      ua.u=r0.x; ub.u=r0.y; fa=__half22float2(ua.h); fb=__half22float2(ub.h);
      a.x+=fa.x; a.y+=fa.y; a.z+=fb.x; a.w+=fb.y;
      ua.u=r1.x; ub.u=r1.y; fa=__half22float2(ua.h); fb=__half22float2(ub.h);
      a.x+=fa.x; a.y+=fa.y; a.z+=fb.x; a.w+=fb.y;
    }
    for (; p < pe; p++){
      int s = csr_src[p];
      uint2 r = *reinterpret_cast<const uint2*>(&Vb[(size_t)s*H]);
      HU ua, ub; ua.u = r.x; ub.u = r.y;
      float2 fa = __half22float2(ua.h), fb = __half22float2(ub.h);
      a.x += fa.x; a.y += fa.y; a.z += fb.x; a.w += fb.y;
    }
    float4* pp = reinterpret_cast<float4*>(&pre[(size_t)node*H + lane*4]);
    float4 pr = *pp;
    pr.x += a.x; pr.y += a.y; pr.z += a.z; pr.w += a.w;
    if (!LAST) *pp = pr;
    h4.x = lrelu(pr.x); h4.y = lrelu(pr.y); h4.z = lrelu(pr.z); h4.w = lrelu(pr.w);
    q4.x = h4.x*h4.x;   q4.y = h4.y*h4.y;   q4.z = h4.z*h4.z;   q4.w = h4.w*h4.w;
  }
  __shared__ float4 red[8][32];
  __shared__ int gsh[2];
  int slot = threadIdx.x >> 5;
  red[slot][lane] = h4;
  if (LAST && threadIdx.x == 0){
    int n0 = blockIdx.x*8;
    int n7 = n0 + 7; if (n7 >= n) n7 = n - 1;
    gsh[0] = batch[n0 < n ? n0 : n-1];
    gsh[1] = batch[n7];
  }
  __syncthreads();
  if (threadIdx.x < 32){
    float4 tt = red[0][threadIdx.x];
    #pragma unroll
    for (int r=1;r<8;r++){
      float4 v = red[r][threadIdx.x];
      tt.x += v.x; tt.y += v.y; tt.z += v.z; tt.w += v.w;
    }
    *reinterpret_cast<float4*>(&partial[(size_t)blockIdx.x*256 + threadIdx.x*4]) = tt;
    if (LAST && gsh[0] == gsh[1]){
      float* pp2 = &pooled[(size_t)gsh[0]*H + threadIdx.x*4];
      atomicAdd(pp2+0, tt.x); atomicAdd(pp2+1, tt.y);
      atomicAdd(pp2+2, tt.z); atomicAdd(pp2+3, tt.w);
    }
  }
  if (LAST && gsh[0] != gsh[1] && node < n){
    int g = batch[node];
    float* pp2 = &pooled[(size_t)g*H + lane*4];
    atomicAdd(pp2+0, h4.x); atomicAdd(pp2+1, h4.y);
    atomicAdd(pp2+2, h4.z); atomicAdd(pp2+3, h4.w);
  }
  __syncthreads();
  red[slot][lane] = q4;
  __syncthreads();
  if (threadIdx.x < 32){
    float4 tt = red[0][threadIdx.x];
    #pragma unroll
    for (int r=1;r<8;r++){
      float4 v = red[r][threadIdx.x];
      tt.x += v.x; tt.y += v.y; tt.z += v.z; tt.w += v.w;
    }
    *reinterpret_cast<float4*>(&partial[(size_t)blockIdx.x*256 + 128 + threadIdx.x*4]) = tt;
  }
}

// ---------- reduce partials -> bnsum[256]; last block finalizes scsh ----------
__global__ __launch_bounds__(256)
void redstats_kernel(const float* __restrict__ partial, int nb, float* __restrict__ bnsum,
                     const float* __restrict__ gamma, const float* __restrict__ beta,
                     float inv_n, float* __restrict__ scsh, int* __restrict__ cnt){
  int c = threadIdx.x;
  float acc = 0.f;
  for (int b = blockIdx.x; b < nb; b += 64)
    acc += partial[(size_t)b*256 + c];
  atomicAdd(&bnsum[c], acc);
  __threadfence();
  __shared__ int lastS;
  __syncthreads();
  if (threadIdx.x == 0){
    int prev = atomicAdd(cnt, 1);
    lastS = (prev == 63) ? 1 : 0;
  }
  __syncthreads();
  if (lastS && c < H){
    float s  = atomicAdd(&bnsum[c], 0.f);       // device-coherent read
    float ss = atomicAdd(&bnsum[H + c], 0.f);
    float mu  = s * inv_n;
    float var = ss * inv_n - mu*mu;
    float rs  = rsqrtf(fmaxf(var, 0.f) + EPSBN);
    float sc  = gamma[c] * rs;
    scsh[c]     = sc;
    scsh[H + c] = beta[c] - mu*sc;
  }
}

// ---------- final MLP head (from raw pooled sums): one block per graph ----------
// pooled mean = (sc * sum_g lrelu(pre) + cnt*sh) / cnt
__global__ __launch_bounds__(128)
void head_kernel(const float* __restrict__ pooled, const float* __restrict__ scsh,
                 const int* __restrict__ gofs,
                 const float* __restrict__ Wf1, const float* __restrict__ bf1,
                 const float* __restrict__ Wf2, const float* __restrict__ bf2,
                 const float* __restrict__ Wf3, const float* __restrict__ bf3,
                 float* __restrict__ out){
  int g = blockIdx.x;
  int c = threadIdx.x;
  __shared__ float pm[128], h1[128], h2[64];
  float cntf = (float)(gofs[g+1] - gofs[g]);
  float cf = fmaxf(cntf, 1.f);
  pm[c] = (scsh[c]*pooled[(size_t)g*H + c] + scsh[H + c]*cntf) / cf;
  __syncthreads();
  float a = bf1[c];
  for (int k=0;k<H;k++) a += pm[k]*Wf1[k*H + c];
  h1[c] = lrelu(a);
  __syncthreads();
  if (c < 64){
    float b = bf2[c];
    for (int k=0;k<H;k++) b += h1[k]*Wf2[k*64 + c];
    h2[c] = lrelu(b);
  }
  __syncthreads();
  if (c < 2){
    float o = bf3[c];
    for (int k=0;k<64;k++) o += h2[k]*Wf3[k*2 + c];
    out[g*2 + c] = o;
  }
}

extern "C" void kernel_launch(void* const* d_in, const int* in_sizes, int n_in,
                              void* d_out, int out_size, void* d_ws, size_t ws_size,
                              hipStream_t stream){
  const float* x     = (const float*)d_in[0];
  const int*   ei    = (const int*)d_in[1];
  const int*   batch = (const int*)d_in[3];
  const float* Wg    = (const float*)d_in[4];
  const float* bg    = (const float*)d_in[5];
  const float* We    = (const float*)d_in[6];
  const float* be    = (const float*)d_in[7];
  const float* Wl    = (const float*)d_in[8];
  const float* bl    = (const float*)d_in[9];
  const float* gamma = (const float*)d_in[10];
  const float* beta  = (const float*)d_in[11];
  const float* Wf1   = (const float*)d_in[12];
  const float* bf1   = (const float*)d_in[13];
  const float* Wf2   = (const float*)d_in[14];
  const float* bf2   = (const float*)d_in[15];
  const float* Wf3   = (const float*)d_in[16];
  const float* bf3   = (const float*)d_in[17];
  float* out = (float*)d_out;

  int n = in_sizes[0] / H;   // 50000
  int E = in_sizes[1] / 2;   // 800000
  int B = out_size / 2;      // 50

  int nagg = (n + 7)/8;      // agg/partial blocks
  int nb   = (n + 255)/256;  // scan blocks
  int nbDeg = (E + 255)/256;

  char* ws = (char*)d_ws;
  size_t off = 0;
  auto alloc = [&](size_t bytes)->void*{ void* p = ws + off; off += (bytes + 255) & ~255ULL; return p; };
  float*  pre    = (float*)alloc((size_t)n*H*4);
  __half* Vh     = (__half*)alloc((size_t)n*H*2);
  float*  Mcomb  = (float*)alloc((size_t)3*H*256*4);
  float*  Ntmp   = (float*)alloc((size_t)3*H*256*4);
  unsigned short* Mfh = (unsigned short*)alloc((size_t)3*4*16*64*8*2);
  unsigned short* Mfl = (unsigned short*)alloc((size_t)3*4*16*64*8*2);
  float*  c1c2   = (float*)alloc(3*2*H*4);
  float*  scsh   = (float*)alloc(3*2*H*4);
  int*    incl   = (int*)alloc((size_t)n*4);
  int*    bsum   = (int*)alloc(256*4);
  int*    rowptr = (int*)alloc((size_t)(n+1)*4);
  unsigned short* rankA   = (unsigned short*)alloc((size_t)E*2);
  unsigned short* csr_src = (unsigned short*)alloc((size_t)E*2);
  int*    gofs   = (int*)alloc((size_t)(B+1)*4);
  float*  partial= (float*)alloc((size_t)nagg*256*4);
  char* zbase = ws + off;                 // ---- zeroed region starts ----
  float* bnsum  = (float*)alloc(3*2*H*4);
  int*   cnt    = (int*)alloc(3*4);
  int*   degI   = (int*)alloc((size_t)n*4);
  float* pooled = (float*)alloc((size_t)B*H*4);
  size_t zbytes = (size_t)((ws + off) - zbase);
  hipMemsetAsync(zbase, 0, zbytes, stream);

  // K1: prep1 | prepc | deg | gofs
  k1_kernel<<<3*H + 3 + nbDeg + nb, 256, 0, stream>>>(We, Wl, Ntmp, be, bg, bl, c1c2,
                                                      ei, E, degI, rankA, batch, n, B, gofs, nbDeg);
  // K2: prep2 | scan1
  k2_kernel<<<3*H + nb, 256, 0, stream>>>(Wg, Ntmp, Mcomb, degI, n, incl, bsum);
  // K3: prep3 | scan2
  k3_kernel<<<3*64 + 1, 256, 0, stream>>>(Mcomb, Mfh, Mfl, bsum, nb);
  scan3_kernel<<<nb, 256, 0, stream>>>(incl, degI, bsum, n, E, rowptr);
  fill_kernel<<<nbDeg, 256, 0, stream>>>(ei, E, rowptr, rankA, csr_src);

  int gblocks = (n + BM - 1)/BM;
  size_t mstride = (size_t)4*16*64*8;   // shorts per layer
  for (int l=0; l<3; l++){
    if (l == 0)
      gemm_kernel<0><<<gblocks, 256, 0, stream>>>(x, nullptr, Mfh, Mfl, c1c2, degI, n, pre, Vh);
    else
      gemm_kernel<1><<<gblocks, 256, 0, stream>>>(pre, scsh + (l-1)*2*H, Mfh + l*mstride, Mfl + l*mstride,
                                                  c1c2 + l*2*H, degI, n, pre, Vh);
    if (l < 2)
      agg_kernel<0><<<nagg, 256, 0, stream>>>(rowptr, csr_src, Vh, pre, n, partial, nullptr, nullptr);
    else
      agg_kernel<1><<<nagg, 256, 0, stream>>>(rowptr, csr_src, Vh, pre, n, partial, batch, pooled);
    redstats_kernel<<<64, 256, 0, stream>>>(partial, nagg, bnsum + l*2*H,
                                            gamma + l*H, beta + l*H, 1.f/(float)n,
                                            scsh + l*2*H, cnt + l);
  }
  head_kernel<<<B, 128, 0, stream>>>(pooled, scsh + 2*2*H, gofs, Wf1, bf1, Wf2, bf2, Wf3, bf3, out);
}

// Round 16
// 327.905 us; speedup vs baseline: 1.5653x; 1.1935x over previous
//
#include <hip/hip_runtime.h>
#include <hip/hip_fp16.h>

#define H 128
#define NEG 0.2f
#define EPSBN 1e-5f
#define BM 32

__device__ __forceinline__ float lrelu(float v){ return v >= 0.f ? v : NEG*v; }

union HU { __half2 h; unsigned int u; };

typedef __attribute__((ext_vector_type(8))) short bf16x8;
typedef __attribute__((ext_vector_type(4))) float f32x4;
#define MFMA16(a,b,c) __builtin_amdgcn_mfma_f32_16x16x32_bf16(a,b,c,0,0,0)

__device__ __forceinline__ unsigned short bf16_rn(float x){
  unsigned int u = __float_as_uint(x);
  u += 0x7fffu + ((u >> 16) & 1u);
  return (unsigned short)(u >> 16);
}
__device__ __forceinline__ float bf16f(unsigned short h){
  return __uint_as_float(((unsigned int)h) << 16);
}

__device__ __forceinline__ void asplit(const float* As, int aofs, bf16x8& ah, bf16x8& al){
  float av[8];
  *reinterpret_cast<float4*>(&av[0]) = *reinterpret_cast<const float4*>(&As[aofs]);
  *reinterpret_cast<float4*>(&av[4]) = *reinterpret_cast<const float4*>(&As[aofs+4]);
  #pragma unroll
  for (int j=0;j<8;j++){
    unsigned short h = bf16_rn(av[j]);
    ah[j] = (short)h;
    al[j] = (short)bf16_rn(av[j] - bf16f(h));
  }
}

// ================= K1: prep1 | prepc | deg | gofs (all independent) =================
__global__ __launch_bounds__(256)
void k1_kernel(const float* __restrict__ We, const float* __restrict__ Wl,
               float* __restrict__ Ntmp,
               const float* __restrict__ be, const float* __restrict__ bg,
               const float* __restrict__ bl, float* __restrict__ c1c2,
               const int* __restrict__ ei, int E, int* __restrict__ degI,
               unsigned short* __restrict__ rankA,
               const int* __restrict__ batch, int n, int B, int* __restrict__ gofs,
               int nbDeg){
  int b = blockIdx.x;
  int t = threadIdx.x;
  if (b < 3*H){
    int l = b >> 7;
    int k = b & 127;
    __shared__ float WeS[2*H];
    if (t < H) WeS[t] = We[(size_t)(l*2*H + k)*H + t];
    else       WeS[t] = We[(size_t)(l*2*H + 128 + k)*H + (t-128)];
    __syncthreads();
    const float* wl = Wl + (size_t)l*H*H;
    int sel = (t >> 7) << 7;
    int jj = t & 127;
    float acc = 0.f;
    #pragma unroll 8
    for (int m=0;m<H;m++) acc += WeS[sel + m] * wl[m*H + jj];
    Ntmp[(size_t)(l*H + k)*256 + t] = acc;
  } else if (b < 3*H + 3){
    int l = b - 3*H;
    if (t < H){
      const float* wl = Wl + (size_t)l*H*H;
      float a1=0.f, a2=0.f;
      for (int m=0;m<H;m++){ float w = wl[m*H + t]; a1 += be[l*H+m]*w; a2 += bg[l*H+m]*w; }
      c1c2[l*2*H + t]     = a1;
      c1c2[l*2*H + H + t] = a2 + bl[l*H + t];
    }
  } else if (b < 3*H + 3 + nbDeg){
    int e = (b - 3*H - 3)*256 + t;
    if (e < E){
      int r = atomicAdd(&degI[ei[E + e]], 1);
      rankA[e] = (unsigned short)r;
    }
  } else {
    int i = (b - 3*H - 3 - nbDeg)*256 + t;
    if (i >= n) return;
    if (i == 0){
      int b0 = batch[0];
      for (int g=0; g<=b0; g++) gofs[g] = 0;
    } else {
      int bp = batch[i-1], bc = batch[i];
      for (int g=bp+1; g<=bc; g++) gofs[g] = i;
    }
    if (i == n-1){
      int bl2 = batch[n-1];
      for (int g=bl2+1; g<=B; g++) gofs[g] = n;
    }
  }
}

// ================= K2: prep2 | scan1 =================
__global__ __launch_bounds__(256)
void k2_kernel(const float* __restrict__ Wg, const float* __restrict__ Ntmp,
               float* __restrict__ Mcomb,
               const int* __restrict__ degI, int n,
               int* __restrict__ incl, int* __restrict__ bsum){
  int b = blockIdx.x;
  int t = threadIdx.x;
  if (b < 3*H){
    int l = b >> 7;
    int k = b & 127;
    __shared__ float WgS[H];
    if (t < H) WgS[t] = Wg[(size_t)(l*H + k)*H + t];
    __syncthreads();
    const float* nt = Ntmp + (size_t)l*H*256;
    float acc = 0.f;
    #pragma unroll 8
    for (int m=0;m<H;m++) acc += WgS[m] * nt[m*256 + t];
    Mcomb[(size_t)(l*H + k)*256 + t] = acc;
  } else {
    int vb = b - 3*H;
    int i = vb*256 + t;
    __shared__ int sh[256];
    int v = (i < n) ? degI[i] : 0;
    sh[t] = v;
    __syncthreads();
    for (int ofs=1; ofs<256; ofs<<=1){
      int tv = (t >= ofs) ? sh[t - ofs] : 0;
      __syncthreads();
      sh[t] += tv;
      __syncthreads();
    }
    if (i < n) incl[i] = sh[t];
    if (t == 255) bsum[vb] = sh[255];
  }
}

// ================= K3: prep3 | scan2 =================
__global__ __launch_bounds__(256)
void k3_kernel(const float* __restrict__ Mcomb,
               unsigned short* __restrict__ Mfh, unsigned short* __restrict__ Mfl,
               int* __restrict__ bsum, int nb){
  int b = blockIdx.x;
  int t = threadIdx.x;
  if (b < 3*64){
    if (t >= 64) return;
    int l  = b >> 6;
    int ks = (b >> 4) & 3;
    int ct = b & 15;
    int lane = t;
    const float* M = Mcomb + (size_t)l*H*256;
    size_t base = ((((size_t)l*4 + ks)*16 + ct)*64 + lane)*8;
    int col = ct*16 + (lane & 15);
    int g = lane >> 4;
    #pragma unroll
    for (int j=0;j<8;j++){
      int k = ks*32 + 8*g + j;
      float v = M[(size_t)k*256 + col];
      unsigned short hi = bf16_rn(v);
      unsigned short lo = bf16_rn(v - bf16f(hi));
      Mfh[base + j] = hi;
      Mfl[base + j] = lo;
    }
  } else {
    __shared__ int sh[256];
    int v = (t < nb) ? bsum[t] : 0;
    sh[t] = v;
    __syncthreads();
    for (int ofs=1; ofs<256; ofs<<=1){
      int tv = (t >= ofs) ? sh[t - ofs] : 0;
      __syncthreads();
      sh[t] += tv;
      __syncthreads();
    }
    if (t < nb) bsum[t] = sh[t] - v;  // exclusive
  }
}

// ---------- scan3: rowptr ----------
__global__ void scan3_kernel(const int* __restrict__ incl, const int* __restrict__ degI,
                             const int* __restrict__ bexcl, int n, int E,
                             int* __restrict__ rowptr){
  int i = blockIdx.x*256 + threadIdx.x;
  if (i < n){
    int start = incl[i] - degI[i] + bexcl[blockIdx.x];
    rowptr[i] = start;
    if (i == n-1) rowptr[n] = E;
  }
}

// ---------- atomic-free fill: pos = rowptr[dst] + rank ----------
__global__ void fill_kernel(const int* __restrict__ ei, int E,
                            const int* __restrict__ rowptr, const unsigned short* __restrict__ rankA,
                            unsigned short* __restrict__ csr_src){
  int e = blockIdx.x*256 + threadIdx.x;
  if (e < E){
    int c = ei[E + e];
    int pos = rowptr[c] + (int)rankA[e];
    csr_src[pos] = (unsigned short)ei[e];
  }
}

// ---------- MFMA GEMM: [U|V] = A @ M (128x256), split-bf16: U 3-term, V 2-term ----------
#define KSBODY(KS, C, N, PREF) \
  { bf16x8 ah, al; asplit(As, arow_*132 + (KS)*32 + agrp, ah, al); \
    if (PREF){ int nb = fb + ((KS)+1)*1024; \
      N##U0h = Bh[nb];     N##U1h = Bh[nb+64];  N##U2h = Bh[nb+128]; N##U3h = Bh[nb+192]; \
      N##U0l = Bl[nb];     N##U1l = Bl[nb+64];  N##U2l = Bl[nb+128]; N##U3l = Bl[nb+192]; \
      N##V0h = Bh[nb+512]; N##V1h = Bh[nb+576]; N##V2h = Bh[nb+640]; N##V3h = Bh[nb+704]; } \
    accU[0]=MFMA16(ah,C##U0h,accU[0]); accU[0]=MFMA16(al,C##U0h,accU[0]); accU[0]=MFMA16(ah,C##U0l,accU[0]); \
    accV[0]=MFMA16(ah,C##V0h,accV[0]); accV[0]=MFMA16(al,C##V0h,accV[0]); \
    accU[1]=MFMA16(ah,C##U1h,accU[1]); accU[1]=MFMA16(al,C##U1h,accU[1]); accU[1]=MFMA16(ah,C##U1l,accU[1]); \
    accV[1]=MFMA16(ah,C##V1h,accV[1]); accV[1]=MFMA16(al,C##V1h,accV[1]); \
    accU[2]=MFMA16(ah,C##U2h,accU[2]); accU[2]=MFMA16(al,C##U2h,accU[2]); accU[2]=MFMA16(ah,C##U2l,accU[2]); \
    accV[2]=MFMA16(ah,C##V2h,accV[2]); accV[2]=MFMA16(al,C##V2h,accV[2]); \
    accU[3]=MFMA16(ah,C##U3h,accU[3]); accU[3]=MFMA16(al,C##U3h,accU[3]); accU[3]=MFMA16(ah,C##U3l,accU[3]); \
    accV[3]=MFMA16(ah,C##V3h,accV[3]); accV[3]=MFMA16(al,C##V3h,accV[3]); }

template<int XF>
__global__ __launch_bounds__(256)
void gemm_kernel(const float* __restrict__ Zin, const float* __restrict__ bnp,
                 const unsigned short* __restrict__ Mfh, const unsigned short* __restrict__ Mfl,
                 const float* __restrict__ c1c2, const int* __restrict__ degI,
                 int n, float* __restrict__ pre, __half* __restrict__ Vh){
  __shared__ float As[32*132];      // [row][k] padded to 132
  int brow = blockIdx.x * BM;
  int t = threadIdx.x;

  int lane = t & 63;
  int w = t >> 6;
  int rowtile = w & 1, colgroup = w >> 1;
  const bf16x8* Bh = reinterpret_cast<const bf16x8*>(Mfh);
  const bf16x8* Bl = reinterpret_cast<const bf16x8*>(Mfl);
  int fb = colgroup*4*64 + lane;    // frag index (ks=0, ct=colgroup*4)

  // ---- issue ks0 B loads early (overlap with A staging) ----
  bf16x8 cU0h,cU1h,cU2h,cU3h, cU0l,cU1l,cU2l,cU3l, cV0h,cV1h,cV2h,cV3h;
  bf16x8 nU0h,nU1h,nU2h,nU3h, nU0l,nU1l,nU2l,nU3l, nV0h,nV1h,nV2h,nV3h;
  cU0h = Bh[fb];     cU1h = Bh[fb+64];  cU2h = Bh[fb+128]; cU3h = Bh[fb+192];
  cU0l = Bl[fb];     cU1l = Bl[fb+64];  cU2l = Bl[fb+128]; cU3l = Bl[fb+192];
  cV0h = Bh[fb+512]; cV1h = Bh[fb+576]; cV2h = Bh[fb+640]; cV3h = Bh[fb+704];

  // ---- stage A (all K) into LDS ----
  {
    int srow = t >> 3, sf = t & 7;
    int gr = brow + srow;
    bool act = (gr < n);
    const float* zrow = Zin + (size_t)gr*H;
    #pragma unroll
    for (int u=0; u<4; u++){
      int c4 = sf + 8*u;            // float4 index 0..31
      float4 g = make_float4(0.f,0.f,0.f,0.f);
      if (act) g = *reinterpret_cast<const float4*>(&zrow[c4*4]);
      if (XF){
        float4 sc4 = *reinterpret_cast<const float4*>(&bnp[c4*4]);
        float4 sh4 = *reinterpret_cast<const float4*>(&bnp[H + c4*4]);
        g.x = lrelu(g.x)*sc4.x + sh4.x;
        g.y = lrelu(g.y)*sc4.y + sh4.y;
        g.z = lrelu(g.z)*sc4.z + sh4.z;
        g.w = lrelu(g.w)*sc4.w + sh4.w;
      }
      *reinterpret_cast<float4*>(&As[srow*132 + c4*4]) = g;
    }
  }
  __syncthreads();

  f32x4 accU[4], accV[4];
  #pragma unroll
  for (int i=0;i<4;i++){
    accU[i] = (f32x4){0.f,0.f,0.f,0.f};
    accV[i] = (f32x4){0.f,0.f,0.f,0.f};
  }
  int arow_ = rowtile*16 + (lane & 15);
  int agrp  = (lane >> 4) << 3;     // 8*(lane>>4)

  KSBODY(0, c, n, 1)
  KSBODY(1, n, c, 1)
  KSBODY(2, c, n, 1)
  KSBODY(3, n, c, 0)

  // ---- epilogue: C/D layout col = lane&15, row = (lane>>4)*4 + reg ----
  int rowbase = brow + rowtile*16 + ((lane >> 4) << 2);
  float dg[4];
  #pragma unroll
  for (int r=0;r<4;r++){
    int gr = rowbase + r;
    dg[r] = (gr < n) ? (float)(degI[gr] + 1) : 0.f;
  }
  #pragma unroll
  for (int ctu=0; ctu<4; ctu++){
    int colU = colgroup*64 + ctu*16 + (lane & 15);
    float c1v = c1c2[colU], c2v = c1c2[H + colU];
    #pragma unroll
    for (int r=0;r<4;r++){
      int gr = rowbase + r;
      if (gr < n){
        float uu = accU[ctu][r], vv = accV[ctu][r];
        pre[(size_t)gr*H + colU] = dg[r]*(uu + c1v) + c2v + vv;
        Vh [(size_t)gr*H + colU] = __float2half(vv);
      }
    }
  }
}

// ---------- CSR aggregation + fused BN-stats partials ----------
// 16 lanes x uint4 (16B) per node, 16 nodes/block; 8-deep gather unroll.
// LAST=1: skip pre write-back, accumulate per-graph pooled sums of lrelu(pre)
#define ACC4(R) { HU ua_, ub_; float2 fa_, fb_; \
  ua_.u=(R).x; fa_=__half22float2(ua_.h); a0+=fa_.x; a1+=fa_.y; \
  ub_.u=(R).y; fb_=__half22float2(ub_.h); a2+=fb_.x; a3+=fb_.y; \
  ua_.u=(R).z; fa_=__half22float2(ua_.h); a4+=fa_.x; a5+=fa_.y; \
  ub_.u=(R).w; fb_=__half22float2(ub_.h); a6+=fb_.x; a7+=fb_.y; }

template<int LAST>
__global__ __launch_bounds__(256)
void agg_kernel(const int* __restrict__ rowptr, const unsigned short* __restrict__ csr_src,
                const __half* __restrict__ Vh, float* __restrict__ pre, int n,
                float* __restrict__ partial,
                const int* __restrict__ batch, float* __restrict__ pooled){
  int node = blockIdx.x*16 + (threadIdx.x >> 4);
  int lane = threadIdx.x & 15;
  float h0=0.f,h1=0.f,h2=0.f,h3=0.f,h4=0.f,h5=0.f,h6=0.f,h7=0.f;
  float q0=0.f,q1=0.f,q2=0.f,q3=0.f,q4=0.f,q5=0.f,q6=0.f,q7=0.f;
  if (node < n){
    int p  = rowptr[node];
    int pe = rowptr[node+1];
    const __half* Vb = Vh + lane*8;
    float a0=0.f,a1=0.f,a2=0.f,a3=0.f,a4=0.f,a5=0.f,a6=0.f,a7=0.f;
    for (; p+8 <= pe; p+=8){
      int s0 = csr_src[p],   s1 = csr_src[p+1], s2 = csr_src[p+2], s3 = csr_src[p+3];
      int s4 = csr_src[p+4], s5 = csr_src[p+5], s6 = csr_src[p+6], s7 = csr_src[p+7];
      uint4 r0 = *reinterpret_cast<const uint4*>(&Vb[(size_t)s0*H]);
      uint4 r1 = *reinterpret_cast<const uint4*>(&Vb[(size_t)s1*H]);
      uint4 r2 = *reinterpret_cast<const uint4*>(&Vb[(size_t)s2*H]);
      uint4 r3 = *reinterpret_cast<const uint4*>(&Vb[(size_t)s3*H]);
      uint4 r4 = *reinterpret_cast<const uint4*>(&Vb[(size_t)s4*H]);
      uint4 r5 = *reinterpret_cast<const uint4*>(&Vb[(size_t)s5*H]);
      uint4 r6 = *reinterpret_cast<const uint4*>(&Vb[(size_t)s6*H]);
      uint4 r7 = *reinterpret_cast<const uint4*>(&Vb[(size_t)s7*H]);
      ACC4(r0) ACC4(r1) ACC4(r2) ACC4(r3)
      ACC4(r4) ACC4(r5) ACC4(r6) ACC4(r7)
    }
    for (; p+2 <= pe; p+=2){
      int s0 = csr_src[p], s1 = csr_src[p+1];
      uint4 r0 = *reinterpret_cast<const uint4*>(&Vb[(size_t)s0*H]);
      uint4 r1 = *reinterpret_cast<const uint4*>(&Vb[(size_t)s1*H]);
      ACC4(r0) ACC4(r1)
    }
    for (; p < pe; p++){
      int s = csr_src[p];
      uint4 r = *reinterpret_cast<const uint4*>(&Vb[(size_t)s*H]);
      ACC4(r)
    }
    float4 pr0 = *reinterpret_cast<const float4*>(&pre[(size_t)node*H + lane*8]);
    float4 pr1 = *reinterpret_cast<const float4*>(&pre[(size_t)node*H + lane*8 + 4]);
    pr0.x += a0; pr0.y += a1; pr0.z += a2; pr0.w += a3;
    pr1.x += a4; pr1.y += a5; pr1.z += a6; pr1.w += a7;
    if (!LAST){
      *reinterpret_cast<float4*>(&pre[(size_t)node*H + lane*8])     = pr0;
      *reinterpret_cast<float4*>(&pre[(size_t)node*H + lane*8 + 4]) = pr1;
    }
    h0 = lrelu(pr0.x); h1 = lrelu(pr0.y); h2 = lrelu(pr0.z); h3 = lrelu(pr0.w);
    h4 = lrelu(pr1.x); h5 = lrelu(pr1.y); h6 = lrelu(pr1.z); h7 = lrelu(pr1.w);
    q0 = h0*h0; q1 = h1*h1; q2 = h2*h2; q3 = h3*h3;
    q4 = h4*h4; q5 = h5*h5; q6 = h6*h6; q7 = h7*h7;
  }
  __shared__ float red[16][132];
  __shared__ int gsh[2];
  int slot = threadIdx.x >> 4;
  if (LAST && threadIdx.x == 0){
    int n0 = blockIdx.x*16;
    int nl = n0 + 15; if (nl >= n) nl = n - 1;
    gsh[0] = batch[n0 < n ? n0 : n-1];
    gsh[1] = batch[nl];
  }
  // ---- h reduction ----
  *reinterpret_cast<float4*>(&red[slot][lane*8])     = make_float4(h0,h1,h2,h3);
  *reinterpret_cast<float4*>(&red[slot][lane*8 + 4]) = make_float4(h4,h5,h6,h7);
  __syncthreads();
  if (threadIdx.x < 128){
    int c = threadIdx.x;
    float tt = 0.f;
    #pragma unroll
    for (int s=0;s<16;s++) tt += red[s][c];
    partial[(size_t)blockIdx.x*256 + c] = tt;
    if (LAST && gsh[0] == gsh[1])
      atomicAdd(&pooled[(size_t)gsh[0]*H + c], tt);
  }
  if (LAST && gsh[0] != gsh[1] && node < n){
    int g = batch[node];
    float* pp2 = &pooled[(size_t)g*H + lane*8];
    atomicAdd(pp2+0, h0); atomicAdd(pp2+1, h1); atomicAdd(pp2+2, h2); atomicAdd(pp2+3, h3);
    atomicAdd(pp2+4, h4); atomicAdd(pp2+5, h5); atomicAdd(pp2+6, h6); atomicAdd(pp2+7, h7);
  }
  __syncthreads();
  // ---- q reduction ----
  *reinterpret_cast<float4*>(&red[slot][lane*8])     = make_float4(q0,q1,q2,q3);
  *reinterpret_cast<float4*>(&red[slot][lane*8 + 4]) = make_float4(q4,q5,q6,q7);
  __syncthreads();
  if (threadIdx.x < 128){
    int c = threadIdx.x;
    float tt = 0.f;
    #pragma unroll
    for (int s=0;s<16;s++) tt += red[s][c];
    partial[(size_t)blockIdx.x*256 + 128 + c] = tt;
  }
}

// ---------- reduce partials -> bnsum[256]; last block finalizes scsh ----------
__global__ __launch_bounds__(256)
void redstats_kernel(const float* __restrict__ partial, int nb, float* __restrict__ bnsum,
                     const float* __restrict__ gamma, const float* __restrict__ beta,
                     float inv_n, float* __restrict__ scsh, int* __restrict__ cnt){
  int c = threadIdx.x;
  float acc = 0.f;
  for (int b = blockIdx.x; b < nb; b += 64)
    acc += partial[(size_t)b*256 + c];
  atomicAdd(&bnsum[c], acc);
  __threadfence();
  __shared__ int lastS;
  __syncthreads();
  if (threadIdx.x == 0){
    int prev = atomicAdd(cnt, 1);
    lastS = (prev == 63) ? 1 : 0;
  }
  __syncthreads();
  if (lastS && c < H){
    float s  = atomicAdd(&bnsum[c], 0.f);       // device-coherent read
    float ss = atomicAdd(&bnsum[H + c], 0.f);
    float mu  = s * inv_n;
    float var = ss * inv_n - mu*mu;
    float rs  = rsqrtf(fmaxf(var, 0.f) + EPSBN);
    float sc  = gamma[c] * rs;
    scsh[c]     = sc;
    scsh[H + c] = beta[c] - mu*sc;
  }
}

// ---------- final MLP head (from raw pooled sums): one block per graph ----------
__global__ __launch_bounds__(128)
void head_kernel(const float* __restrict__ pooled, const float* __restrict__ scsh,
                 const int* __restrict__ gofs,
                 const float* __restrict__ Wf1, const float* __restrict__ bf1,
                 const float* __restrict__ Wf2, const float* __restrict__ bf2,
                 const float* __restrict__ Wf3, const float* __restrict__ bf3,
                 float* __restrict__ out){
  int g = blockIdx.x;
  int c = threadIdx.x;
  __shared__ float pm[128], h1[128], h2[64];
  float cntf = (float)(gofs[g+1] - gofs[g]);
  float cf = fmaxf(cntf, 1.f);
  pm[c] = (scsh[c]*pooled[(size_t)g*H + c] + scsh[H + c]*cntf) / cf;
  __syncthreads();
  float a = bf1[c];
  for (int k=0;k<H;k++) a += pm[k]*Wf1[k*H + c];
  h1[c] = lrelu(a);
  __syncthreads();
  if (c < 64){
    float b = bf2[c];
    for (int k=0;k<H;k++) b += h1[k]*Wf2[k*64 + c];
    h2[c] = lrelu(b);
  }
  __syncthreads();
  if (c < 2){
    float o = bf3[c];
    for (int k=0;k<64;k++) o += h2[k]*Wf3[k*2 + c];
    out[g*2 + c] = o;
  }
}

extern "C" void kernel_launch(void* const* d_in, const int* in_sizes, int n_in,
                              void* d_out, int out_size, void* d_ws, size_t ws_size,
                              hipStream_t stream){
  const float* x     = (const float*)d_in[0];
  const int*   ei    = (const int*)d_in[1];
  const int*   batch = (const int*)d_in[3];
  const float* Wg    = (const float*)d_in[4];
  const float* bg    = (const float*)d_in[5];
  const float* We    = (const float*)d_in[6];
  const float* be    = (const float*)d_in[7];
  const float* Wl    = (const float*)d_in[8];
  const float* bl    = (const float*)d_in[9];
  const float* gamma = (const float*)d_in[10];
  const float* beta  = (const float*)d_in[11];
  const float* Wf1   = (const float*)d_in[12];
  const float* bf1   = (const float*)d_in[13];
  const float* Wf2   = (const float*)d_in[14];
  const float* bf2   = (const float*)d_in[15];
  const float* Wf3   = (const float*)d_in[16];
  const float* bf3   = (const float*)d_in[17];
  float* out = (float*)d_out;

  int n = in_sizes[0] / H;   // 50000
  int E = in_sizes[1] / 2;   // 800000
  int B = out_size / 2;      // 50

  int nagg = (n + 15)/16;    // agg/partial blocks (16 nodes/block)
  int nb   = (n + 255)/256;  // scan blocks
  int nbDeg = (E + 255)/256;

  char* ws = (char*)d_ws;
  size_t off = 0;
  auto alloc = [&](size_t bytes)->void*{ void* p = ws + off; off += (bytes + 255) & ~255ULL; return p; };
  float*  pre    = (float*)alloc((size_t)n*H*4);
  __half* Vh     = (__half*)alloc((size_t)n*H*2);
  float*  Mcomb  = (float*)alloc((size_t)3*H*256*4);
  float*  Ntmp   = (float*)alloc((size_t)3*H*256*4);
  unsigned short* Mfh = (unsigned short*)alloc((size_t)3*4*16*64*8*2);
  unsigned short* Mfl = (unsigned short*)alloc((size_t)3*4*16*64*8*2);
  float*  c1c2   = (float*)alloc(3*2*H*4);
  float*  scsh   = (float*)alloc(3*2*H*4);
  int*    incl   = (int*)alloc((size_t)n*4);
  int*    bsum   = (int*)alloc(256*4);
  int*    rowptr = (int*)alloc((size_t)(n+1)*4);
  unsigned short* rankA   = (unsigned short*)alloc((size_t)E*2);
  unsigned short* csr_src = (unsigned short*)alloc((size_t)E*2);
  int*    gofs   = (int*)alloc((size_t)(B+1)*4);
  float*  partial= (float*)alloc((size_t)nagg*256*4);
  char* zbase = ws + off;                 // ---- zeroed region starts ----
  float* bnsum  = (float*)alloc(3*2*H*4);
  int*   cnt    = (int*)alloc(3*4);
  int*   degI   = (int*)alloc((size_t)n*4);
  float* pooled = (float*)alloc((size_t)B*H*4);
  size_t zbytes = (size_t)((ws + off) - zbase);
  hipMemsetAsync(zbase, 0, zbytes, stream);

  // K1: prep1 | prepc | deg | gofs
  k1_kernel<<<3*H + 3 + nbDeg + nb, 256, 0, stream>>>(We, Wl, Ntmp, be, bg, bl, c1c2,
                                                      ei, E, degI, rankA, batch, n, B, gofs, nbDeg);
  // K2: prep2 | scan1
  k2_kernel<<<3*H + nb, 256, 0, stream>>>(Wg, Ntmp, Mcomb, degI, n, incl, bsum);
  // K3: prep3 | scan2
  k3_kernel<<<3*64 + 1, 256, 0, stream>>>(Mcomb, Mfh, Mfl, bsum, nb);
  scan3_kernel<<<nb, 256, 0, stream>>>(incl, degI, bsum, n, E, rowptr);
  fill_kernel<<<nbDeg, 256, 0, stream>>>(ei, E, rowptr, rankA, csr_src);

  int gblocks = (n + BM - 1)/BM;
  size_t mstride = (size_t)4*16*64*8;   // shorts per layer
  for (int l=0; l<3; l++){
    if (l == 0)
      gemm_kernel<0><<<gblocks, 256, 0, stream>>>(x, nullptr, Mfh, Mfl, c1c2, degI, n, pre, Vh);
    else
      gemm_kernel<1><<<gblocks, 256, 0, stream>>>(pre, scsh + (l-1)*2*H, Mfh + l*mstride, Mfl + l*mstride,
                                                  c1c2 + l*2*H, degI, n, pre, Vh);
    if (l < 2)
      agg_kernel<0><<<nagg, 256, 0, stream>>>(rowptr, csr_src, Vh, pre, n, partial, nullptr, nullptr);
    else
      agg_kernel<1><<<nagg, 256, 0, stream>>>(rowptr, csr_src, Vh, pre, n, partial, batch, pooled);
    redstats_kernel<<<64, 256, 0, stream>>>(partial, nagg, bnsum + l*2*H,
                                            gamma + l*H, beta + l*H, 1.f/(float)n,
                                            scsh + l*2*H, cnt + l);
  }
  head_kernel<<<B, 128, 0, stream>>>(pooled, scsh + 2*2*H, gofs, Wf1, bf1, Wf2, bf2, Wf3, bf3, out);
}